// Round 1
// baseline (17521.513 us; speedup 1.0000x reference)
//
#include <hip/hip_runtime.h>

// SRM constants (match reference: float(np.exp(-1/16)), float(np.exp(-1/4)))
#define DM 0.9394130628134758f
#define DSC 0.7788007830714049f
#define TH 0.3f

#define B 16
#define T 16

// element counts
#define N0 (16*64*64*64)      // 4,194,304
#define N1 (16*128*64*64)     // 8,388,608
#define N2 (16*128*32*32)     // 2,097,152
#define N3 (16*512)           // 8,192
#define N4 (16*11)            // 176
#define P2N (16*32768)        // 524,288
#define I3PN (8*8192)         // 65,536

__device__ __forceinline__ void srm(float& m, float& s, float p, float I, float& spk) {
    m = DM * m * (1.f - p) + I;
    s = DSC * s * (1.f - p) + I;
    spk = (m - s > TH) ? 1.f : 0.f;
}

// ---------------- conv0: [B,2,64,64] -> [B,64,64,64], 3x3 pad1, + SRM ----------------
__global__ __launch_bounds__(256) void k_conv0(const float* __restrict__ in,
                                               const float* __restrict__ W0,
                                               float* __restrict__ vm, float* __restrict__ vs,
                                               float* __restrict__ sp, int t) {
    int idx = blockIdx.x * 256 + threadIdx.x;          // over N0
    int x = idx & 63, y = (idx >> 6) & 63, co = (idx >> 12) & 63, b = idx >> 18;
    const float* ip = in + ((size_t)(b * T + t) * 2) * 4096;
    float I = 0.f;
#pragma unroll
    for (int ci = 0; ci < 2; ci++) {
        const float* ipc = ip + ci * 4096;
        const float* w = W0 + (co * 2 + ci) * 9;
#pragma unroll
        for (int dy = 0; dy < 3; dy++) {
            int gy = y + dy - 1;
            if (gy < 0 || gy > 63) continue;
#pragma unroll
            for (int dx = 0; dx < 3; dx++) {
                int gx = x + dx - 1;
                if (gx < 0 || gx > 63) continue;
                float v = ipc[gy * 64 + gx];
                v = fminf(fmaxf(v, 0.f), 1.f);          // clip(xt,0,1)
                I += w[dy * 3 + dx] * v;
            }
        }
    }
    float m = vm[idx], s = vs[idx], p = sp[idx], spk;
    srm(m, s, p, I, spk);
    vm[idx] = m; vs[idx] = s; sp[idx] = spk;
}

// ---------------- conv1: [B,64,64,64] -> [B,128,64,64] + SRM ----------------
// grid: B*128*4 blocks (4 y-tiles of 16), 256 thr; thread computes 4 x-outputs.
__global__ __launch_bounds__(256) void k_conv1(const float* __restrict__ s0,
                                               const float* __restrict__ W1,
                                               float* __restrict__ vm, float* __restrict__ vs,
                                               float* __restrict__ sp) {
    __shared__ float tile[18 * 66];
    int bid = blockIdx.x;
    int yt = bid & 3, co = (bid >> 2) & 127, b = bid >> 9;
    int tid = threadIdx.x;
    int tx = (tid & 15) * 4;     // 0..60
    int ty = tid >> 4;           // 0..15
    int y0 = yt * 16;
    float a0 = 0, a1 = 0, a2 = 0, a3 = 0;
    for (int ci = 0; ci < 64; ci++) {
        const float* src = s0 + ((size_t)(b * 64 + ci)) * 4096;
        for (int i = tid; i < 18 * 66; i += 256) {
            int r = i / 66, c = i - r * 66;
            int gy = y0 + r - 1, gx = c - 1;
            float v = 0.f;
            if (gy >= 0 && gy < 64 && gx >= 0 && gx < 64) v = src[gy * 64 + gx];
            tile[i] = v;
        }
        __syncthreads();
        const float* w = W1 + (co * 64 + ci) * 9;
#pragma unroll
        for (int dy = 0; dy < 3; dy++) {
            const float* row = &tile[(ty + dy) * 66 + tx];
            float r0 = row[0], r1 = row[1], r2 = row[2], r3 = row[3], r4 = row[4], r5 = row[5];
            float wa = w[dy * 3], wb = w[dy * 3 + 1], wc = w[dy * 3 + 2];
            a0 += wa * r0 + wb * r1 + wc * r2;
            a1 += wa * r1 + wb * r2 + wc * r3;
            a2 += wa * r2 + wb * r3 + wc * r4;
            a3 += wa * r3 + wb * r4 + wc * r5;
        }
        __syncthreads();
    }
    int obase = ((b * 128 + co) * 64 + (y0 + ty)) * 64 + tx;
    float4 m4 = *(float4*)&vm[obase];
    float4 s4 = *(float4*)&vs[obase];
    float4 p4 = *(float4*)&sp[obase];
    float k0, k1, k2, k3;
    srm(m4.x, s4.x, p4.x, a0, k0);
    srm(m4.y, s4.y, p4.y, a1, k1);
    srm(m4.z, s4.z, p4.z, a2, k2);
    srm(m4.w, s4.w, p4.w, a3, k3);
    *(float4*)&vm[obase] = m4;
    *(float4*)&vs[obase] = s4;
    *(float4*)&sp[obase] = make_float4(k0, k1, k2, k3);
}

// ---------------- pool1: [B,128,64,64] -> [B,128,32,32] ----------------
__global__ __launch_bounds__(256) void k_pool1(const float* __restrict__ s1, float* __restrict__ p1) {
    int idx = blockIdx.x * 256 + threadIdx.x;          // over N2
    int x = idx & 31, y = (idx >> 5) & 31, bc = idx >> 10;
    const float* src = s1 + ((size_t)bc * 64 + 2 * y) * 64 + 2 * x;
    float v = fmaxf(fmaxf(src[0], src[1]), fmaxf(src[64], src[65]));
    p1[idx] = v;
}

// ---------------- conv2: [B,128,32,32] -> [B,128,32,32] + SRM ----------------
// grid: B*128 blocks, 256 thr; thread computes 4 x-outputs; full 32x32 tile.
__global__ __launch_bounds__(256) void k_conv2(const float* __restrict__ p1,
                                               const float* __restrict__ W2,
                                               float* __restrict__ vm, float* __restrict__ vs,
                                               float* __restrict__ sp) {
    __shared__ float tile[34 * 34];
    int co = blockIdx.x & 127, b = blockIdx.x >> 7;
    int tid = threadIdx.x;
    int tx = (tid & 7) * 4;      // 0..28
    int ty = tid >> 3;           // 0..31
    float a0 = 0, a1 = 0, a2 = 0, a3 = 0;
    for (int ci = 0; ci < 128; ci++) {
        const float* src = p1 + ((size_t)(b * 128 + ci)) * 1024;
        for (int i = tid; i < 34 * 34; i += 256) {
            int r = i / 34, c = i - r * 34;
            int gy = r - 1, gx = c - 1;
            float v = 0.f;
            if (gy >= 0 && gy < 32 && gx >= 0 && gx < 32) v = src[gy * 32 + gx];
            tile[i] = v;
        }
        __syncthreads();
        const float* w = W2 + (co * 128 + ci) * 9;
#pragma unroll
        for (int dy = 0; dy < 3; dy++) {
            const float* row = &tile[(ty + dy) * 34 + tx];
            float r0 = row[0], r1 = row[1], r2 = row[2], r3 = row[3], r4 = row[4], r5 = row[5];
            float wa = w[dy * 3], wb = w[dy * 3 + 1], wc = w[dy * 3 + 2];
            a0 += wa * r0 + wb * r1 + wc * r2;
            a1 += wa * r1 + wb * r2 + wc * r3;
            a2 += wa * r2 + wb * r3 + wc * r4;
            a3 += wa * r3 + wb * r4 + wc * r5;
        }
        __syncthreads();
    }
    int obase = ((b * 128 + co) * 32 + ty) * 32 + tx;
    float4 m4 = *(float4*)&vm[obase];
    float4 s4 = *(float4*)&vs[obase];
    float4 p4 = *(float4*)&sp[obase];
    float k0, k1, k2, k3;
    srm(m4.x, s4.x, p4.x, a0, k0);
    srm(m4.y, s4.y, p4.y, a1, k1);
    srm(m4.z, s4.z, p4.z, a2, k2);
    srm(m4.w, s4.w, p4.w, a3, k3);
    *(float4*)&vm[obase] = m4;
    *(float4*)&vs[obase] = s4;
    *(float4*)&sp[obase] = make_float4(k0, k1, k2, k3);
}

// ---------------- pool2: [B,128,32,32] -> p2 [B,32768] ----------------
__global__ __launch_bounds__(256) void k_pool2(const float* __restrict__ s2, float* __restrict__ p2) {
    int idx = blockIdx.x * 256 + threadIdx.x;          // over P2N, layout [b][c][y][x] 16x16
    int x = idx & 15, y = (idx >> 4) & 15, bc = idx >> 8;
    const float* src = s2 + ((size_t)bc * 32 + 2 * y) * 32 + 2 * x;
    float v = fmaxf(fmaxf(src[0], src[1]), fmaxf(src[32], src[33]));
    p2[idx] = v;
}

// ---------------- fc3 partial: p2[16,32768] @ W3^T -> I3p[8][16][512] ----------------
// grid 256 = 32 o-tiles x 8 k-splits; block 256 = 16 o x 16 b
__global__ __launch_bounds__(256) void k_fc3(const float* __restrict__ p2,
                                             const float* __restrict__ W3,
                                             float* __restrict__ I3p) {
    int ot = blockIdx.x & 31, ks = blockIdx.x >> 5;
    int b = threadIdx.x & 15, o = ot * 16 + (threadIdx.x >> 4);
    const float4* w4 = (const float4*)(W3 + (size_t)o * 32768 + ks * 4096);
    const float4* p4 = (const float4*)(p2 + (size_t)b * 32768 + ks * 4096);
    float acc = 0.f;
    for (int k = 0; k < 1024; k++) {
        float4 a = w4[k], c = p4[k];
        acc += a.x * c.x + a.y * c.y + a.z * c.z + a.w * c.w;
    }
    I3p[ks * 8192 + b * 512 + o] = acc;
}

// ---------------- srm3: reduce 8 partials + SRM -> sp3 [16,512] ----------------
__global__ __launch_bounds__(256) void k_srm3(const float* __restrict__ I3p,
                                              float* __restrict__ vm, float* __restrict__ vs,
                                              float* __restrict__ sp) {
    int idx = blockIdx.x * 256 + threadIdx.x;          // over N3
    float I = 0.f;
#pragma unroll
    for (int s = 0; s < 8; s++) I += I3p[s * 8192 + idx];
    float m = vm[idx], s_ = vs[idx], p = sp[idx], spk;
    srm(m, s_, p, I, spk);
    vm[idx] = m; vs[idx] = s_; sp[idx] = spk;
}

// ---------------- fc4 + srm4 + accumulate: sp3[16,512] @ W4^T -> out ----------------
__global__ __launch_bounds__(256) void k_fc4(const float* __restrict__ sp3,
                                             const float* __restrict__ W4,
                                             float* __restrict__ vm, float* __restrict__ vs,
                                             float* __restrict__ sp, float* __restrict__ out) {
    int tid = threadIdx.x;
    if (tid >= N4) return;
    int b = tid / 11, o = tid - b * 11;
    const float* a = sp3 + b * 512;
    const float* w = W4 + o * 512;
    float acc = 0.f;
    for (int k = 0; k < 512; k++) acc += a[k] * w[k];
    float m = vm[tid], s = vs[tid], p = sp[tid], spk;
    srm(m, s, p, acc, spk);
    vm[tid] = m; vs[tid] = s; sp[tid] = spk;
    out[tid] += spk * 0.0625f;   // /num_steps, exact in fp32
}

extern "C" void kernel_launch(void* const* d_in, const int* in_sizes, int n_in,
                              void* d_out, int out_size, void* d_ws, size_t ws_size,
                              hipStream_t stream) {
    const float* in = (const float*)d_in[0];
    const float* W0 = (const float*)d_in[1];
    const float* W1 = (const float*)d_in[2];
    const float* W2 = (const float*)d_in[3];
    const float* W3 = (const float*)d_in[4];
    const float* W4 = (const float*)d_in[5];
    float* out = (float*)d_out;
    float* ws = (float*)d_ws;

    size_t off = 0;
    auto alloc = [&](size_t n) { float* p = ws + off; off += n; return p; };
    float *vm0 = alloc(N0), *vs0 = alloc(N0), *sp0 = alloc(N0);
    float *vm1 = alloc(N1), *vs1 = alloc(N1), *sp1 = alloc(N1);
    float *vm2 = alloc(N2), *vs2 = alloc(N2), *sp2 = alloc(N2);
    float *vm3 = alloc(N3), *vs3 = alloc(N3), *sp3 = alloc(N3);
    float *vm4 = alloc(N4), *vs4 = alloc(N4), *sp4 = alloc(N4);
    size_t state_bytes = off * sizeof(float);
    float *p1 = alloc(N2), *p2 = alloc(P2N), *I3p = alloc(I3PN);

    // zero SRM state + output accumulator (ws/out are poisoned before every call)
    hipMemsetAsync(d_ws, 0, state_bytes, stream);
    hipMemsetAsync(d_out, 0, N4 * sizeof(float), stream);

    for (int t = 0; t < T; t++) {
        k_conv0<<<N0 / 256, 256, 0, stream>>>(in, W0, vm0, vs0, sp0, t);
        k_conv1<<<B * 128 * 4, 256, 0, stream>>>(sp0, W1, vm1, vs1, sp1);
        k_pool1<<<N2 / 256, 256, 0, stream>>>(sp1, p1);
        k_conv2<<<B * 128, 256, 0, stream>>>(p1, W2, vm2, vs2, sp2);
        k_pool2<<<P2N / 256, 256, 0, stream>>>(sp2, p2);
        k_fc3<<<256, 256, 0, stream>>>(p2, W3, I3p);
        k_srm3<<<N3 / 256, 256, 0, stream>>>(I3p, vm3, vs3, sp3);
        k_fc4<<<1, 256, 0, stream>>>(sp3, W4, vm4, vs4, sp4, out);
    }
}

// Round 2
// 12822.736 us; speedup vs baseline: 1.3664x; 1.3664x over previous
//
#include <hip/hip_runtime.h>

// SRM constants (match reference: float(np.exp(-1/16)), float(np.exp(-1/4)))
#define DM 0.9394130628134758f
#define DSC 0.7788007830714049f
#define TH 0.3f

#define B 16
#define T 16

// element counts
#define N0 (16*64*64*64)      // 4,194,304
#define N1 (16*128*64*64)     // 8,388,608
#define N2 (16*128*32*32)     // 2,097,152
#define N3 (16*512)           // 8,192
#define N4 (16*11)            // 176
#define P2N (16*32768)        // 524,288
#define I3PN (8*8192)         // 65,536

__device__ __forceinline__ void srm(float& m, float& s, float p, float I, float& spk) {
    m = DM * m * (1.f - p) + I;
    s = DSC * s * (1.f - p) + I;
    spk = (m - s > TH) ? 1.f : 0.f;
}

// ============ conv0: [B,2,64,64](clip) -> [B,64,64,64] + SRM ============
// grid: B*4yt*8cog = 512 blocks. Each block: 16 rows x 64 cols x 8 co.
#define S0 68
__global__ __launch_bounds__(256) void k_conv0(const float* __restrict__ in,
                                               const float* __restrict__ W0,
                                               float* __restrict__ vm, float* __restrict__ vs,
                                               float* __restrict__ sp, int t) {
    __shared__ float tile[2][18 * S0];
    int bid = blockIdx.x;
    int cog = bid & 7, yt = (bid >> 3) & 3, b = bid >> 5;
    int tid = threadIdx.x;
    int tx = (tid & 15) * 4, ty = tid >> 4, y0 = yt * 16;

    // stage 2 input channels with clip
    for (int cl = 0; cl < 2; cl++) {
        const float* src = in + ((size_t)((b * T + t) * 2 + cl)) * 4096;
        for (int i = tid; i < 18 * 66; i += 256) {
            int r = i / 66, c = i - r * 66;
            int gy = y0 + r - 1, gx = c - 1;
            float v = 0.f;
            if ((unsigned)gy < 64u && (unsigned)gx < 64u)
                v = fminf(fmaxf(src[gy * 64 + gx], 0.f), 1.f);
            tile[cl][r * S0 + c] = v;
        }
    }
    __syncthreads();

    float acc[8][4] = {};
#pragma unroll
    for (int cl = 0; cl < 2; cl++) {
        const float* wb = W0 + ((size_t)cog * 8 * 2 + cl) * 9;
#pragma unroll
        for (int dy = 0; dy < 3; dy++) {
            float4 A = *(const float4*)&tile[cl][(ty + dy) * S0 + tx];
            float4 Bv = *(const float4*)&tile[cl][(ty + dy) * S0 + tx + 4];
            float r0 = A.x, r1 = A.y, r2 = A.z, r3 = A.w, r4 = Bv.x, r5 = Bv.y;
#pragma unroll
            for (int c = 0; c < 8; c++) {
                const float* w = wb + (size_t)c * 2 * 9 + dy * 3;
                float wa = w[0], wbx = w[1], wc = w[2];
                acc[c][0] += wa * r0 + wbx * r1 + wc * r2;
                acc[c][1] += wa * r1 + wbx * r2 + wc * r3;
                acc[c][2] += wa * r2 + wbx * r3 + wc * r4;
                acc[c][3] += wa * r3 + wbx * r4 + wc * r5;
            }
        }
    }

    int y = y0 + ty;
#pragma unroll
    for (int c = 0; c < 8; c++) {
        int co = cog * 8 + c;
        size_t obase = (((size_t)b * 64 + co) * 64 + y) * 64 + tx;
        float4 m4 = *(float4*)&vm[obase];
        float4 s4 = *(float4*)&vs[obase];
        float4 p4 = *(float4*)&sp[obase];
        float k0, k1, k2, k3;
        srm(m4.x, s4.x, p4.x, acc[c][0], k0);
        srm(m4.y, s4.y, p4.y, acc[c][1], k1);
        srm(m4.z, s4.z, p4.z, acc[c][2], k2);
        srm(m4.w, s4.w, p4.w, acc[c][3], k3);
        *(float4*)&vm[obase] = m4;
        *(float4*)&vs[obase] = s4;
        *(float4*)&sp[obase] = make_float4(k0, k1, k2, k3);
    }
}

// ============ conv1: [B,64,64,64] -> [B,128,64,64] + SRM + fused pool1 ============
// grid: B*4yt*16cog = 1024 blocks. Block: 16 rows x 64 cols x 8 co. ci chunks of 8.
#define S1 68
__global__ __launch_bounds__(256, 4) void k_conv1(const float* __restrict__ s0,
                                                  const float* __restrict__ W1,
                                                  float* __restrict__ vm, float* __restrict__ vs,
                                                  float* __restrict__ sp, float* __restrict__ p1) {
    __shared__ float tile[8][18 * S1];
    int bid = blockIdx.x;
    int cog = bid & 15, yt = (bid >> 4) & 3, b = bid >> 6;
    int tid = threadIdx.x;
    int tx = (tid & 15) * 4, ty = tid >> 4, y0 = yt * 16;

    float acc[8][4] = {};
    for (int ch = 0; ch < 8; ch++) {
        for (int cl = 0; cl < 8; cl++) {
            const float* src = s0 + ((size_t)(b * 64 + ch * 8 + cl)) * 4096;
            for (int i = tid; i < 18 * 66; i += 256) {
                int r = i / 66, c = i - r * 66;
                int gy = y0 + r - 1, gx = c - 1;
                float v = 0.f;
                if ((unsigned)gy < 64u && (unsigned)gx < 64u) v = src[gy * 64 + gx];
                tile[cl][r * S1 + c] = v;
            }
        }
        __syncthreads();
        for (int cl = 0; cl < 8; cl++) {
            int ci = ch * 8 + cl;
            const float* wb = W1 + ((size_t)cog * 8 * 64 + ci) * 9;
#pragma unroll
            for (int dy = 0; dy < 3; dy++) {
                float4 A = *(const float4*)&tile[cl][(ty + dy) * S1 + tx];
                float4 Bv = *(const float4*)&tile[cl][(ty + dy) * S1 + tx + 4];
                float r0 = A.x, r1 = A.y, r2 = A.z, r3 = A.w, r4 = Bv.x, r5 = Bv.y;
#pragma unroll
                for (int c = 0; c < 8; c++) {
                    const float* w = wb + (size_t)c * 64 * 9 + dy * 3;
                    float wa = w[0], wbx = w[1], wc = w[2];
                    acc[c][0] += wa * r0 + wbx * r1 + wc * r2;
                    acc[c][1] += wa * r1 + wbx * r2 + wc * r3;
                    acc[c][2] += wa * r2 + wbx * r3 + wc * r4;
                    acc[c][3] += wa * r3 + wbx * r4 + wc * r5;
                }
            }
        }
        __syncthreads();
    }

    int y = y0 + ty;
#pragma unroll
    for (int c = 0; c < 8; c++) {
        int co = cog * 8 + c;
        size_t obase = (((size_t)b * 128 + co) * 64 + y) * 64 + tx;
        float4 m4 = *(float4*)&vm[obase];
        float4 s4 = *(float4*)&vs[obase];
        float4 p4 = *(float4*)&sp[obase];
        float k0, k1, k2, k3;
        srm(m4.x, s4.x, p4.x, acc[c][0], k0);
        srm(m4.y, s4.y, p4.y, acc[c][1], k1);
        srm(m4.z, s4.z, p4.z, acc[c][2], k2);
        srm(m4.w, s4.w, p4.w, acc[c][3], k3);
        *(float4*)&vm[obase] = m4;
        *(float4*)&vs[obase] = s4;
        *(float4*)&sp[obase] = make_float4(k0, k1, k2, k3);
        // fused maxpool 2x2: horizontal in-thread, vertical via shfl with ty^1 lane
        float h0 = fmaxf(k0, k1), h1 = fmaxf(k2, k3);
        float g0 = __shfl_xor(h0, 16);
        float g1 = __shfl_xor(h1, 16);
        if (!(ty & 1)) {
            float2 pv = make_float2(fmaxf(h0, g0), fmaxf(h1, g1));
            *(float2*)&p1[(((size_t)b * 128 + co) * 32 + (y >> 1)) * 32 + (tx >> 1)] = pv;
        }
    }
}

// ============ conv2: [B,128,32,32] -> [B,128,32,32] + SRM + fused pool2 ============
// grid: B*16cog = 256 blocks. Block: 32x32 x 8 co. ci chunks of 8 (16 chunks).
#define S2 36
__global__ __launch_bounds__(256) void k_conv2(const float* __restrict__ p1,
                                               const float* __restrict__ W2,
                                               float* __restrict__ vm, float* __restrict__ vs,
                                               float* __restrict__ sp, float* __restrict__ p2) {
    __shared__ float tile[8][34 * S2];
    int bid = blockIdx.x;
    int cog = bid & 15, b = bid >> 4;
    int tid = threadIdx.x;
    int tx = (tid & 7) * 4, ty = tid >> 3;

    float acc[8][4] = {};
    for (int ch = 0; ch < 16; ch++) {
        for (int cl = 0; cl < 8; cl++) {
            const float* src = p1 + ((size_t)(b * 128 + ch * 8 + cl)) * 1024;
            for (int i = tid; i < 34 * 34; i += 256) {
                int r = i / 34, c = i - r * 34;
                int gy = r - 1, gx = c - 1;
                float v = 0.f;
                if ((unsigned)gy < 32u && (unsigned)gx < 32u) v = src[gy * 32 + gx];
                tile[cl][r * S2 + c] = v;
            }
        }
        __syncthreads();
        for (int cl = 0; cl < 8; cl++) {
            int ci = ch * 8 + cl;
            const float* wb = W2 + ((size_t)cog * 8 * 128 + ci) * 9;
#pragma unroll
            for (int dy = 0; dy < 3; dy++) {
                float4 A = *(const float4*)&tile[cl][(ty + dy) * S2 + tx];
                float4 Bv = *(const float4*)&tile[cl][(ty + dy) * S2 + tx + 4];
                float r0 = A.x, r1 = A.y, r2 = A.z, r3 = A.w, r4 = Bv.x, r5 = Bv.y;
#pragma unroll
                for (int c = 0; c < 8; c++) {
                    const float* w = wb + (size_t)c * 128 * 9 + dy * 3;
                    float wa = w[0], wbx = w[1], wc = w[2];
                    acc[c][0] += wa * r0 + wbx * r1 + wc * r2;
                    acc[c][1] += wa * r1 + wbx * r2 + wc * r3;
                    acc[c][2] += wa * r2 + wbx * r3 + wc * r4;
                    acc[c][3] += wa * r3 + wbx * r4 + wc * r5;
                }
            }
        }
        __syncthreads();
    }

#pragma unroll
    for (int c = 0; c < 8; c++) {
        int co = cog * 8 + c;
        size_t obase = (((size_t)b * 128 + co) * 32 + ty) * 32 + tx;
        float4 m4 = *(float4*)&vm[obase];
        float4 s4 = *(float4*)&vs[obase];
        float4 p4 = *(float4*)&sp[obase];
        float k0, k1, k2, k3;
        srm(m4.x, s4.x, p4.x, acc[c][0], k0);
        srm(m4.y, s4.y, p4.y, acc[c][1], k1);
        srm(m4.z, s4.z, p4.z, acc[c][2], k2);
        srm(m4.w, s4.w, p4.w, acc[c][3], k3);
        *(float4*)&vm[obase] = m4;
        *(float4*)&vs[obase] = s4;
        *(float4*)&sp[obase] = make_float4(k0, k1, k2, k3);
        // fused maxpool 2x2 -> p2 [b][co][16][16]
        float h0 = fmaxf(k0, k1), h1 = fmaxf(k2, k3);
        float g0 = __shfl_xor(h0, 8);
        float g1 = __shfl_xor(h1, 8);
        if (!(ty & 1)) {
            float2 pv = make_float2(fmaxf(h0, g0), fmaxf(h1, g1));
            *(float2*)&p2[(size_t)b * 32768 + co * 256 + (ty >> 1) * 16 + (tx >> 1)] = pv;
        }
    }
}

// ============ fc3 partial: p2[16,32768] @ W3^T -> I3p[8][16][512] ============
__global__ __launch_bounds__(256) void k_fc3(const float* __restrict__ p2,
                                             const float* __restrict__ W3,
                                             float* __restrict__ I3p) {
    int ot = blockIdx.x & 31, ks = blockIdx.x >> 5;
    int b = threadIdx.x & 15, o = ot * 16 + (threadIdx.x >> 4);
    const float4* w4 = (const float4*)(W3 + (size_t)o * 32768 + ks * 4096);
    const float4* p4 = (const float4*)(p2 + (size_t)b * 32768 + ks * 4096);
    float acc = 0.f;
    for (int k = 0; k < 1024; k++) {
        float4 a = w4[k], c = p4[k];
        acc += a.x * c.x + a.y * c.y + a.z * c.z + a.w * c.w;
    }
    I3p[ks * 8192 + b * 512 + o] = acc;
}

// ============ srm3: reduce 8 partials + SRM -> sp3 [16,512] ============
__global__ __launch_bounds__(256) void k_srm3(const float* __restrict__ I3p,
                                              float* __restrict__ vm, float* __restrict__ vs,
                                              float* __restrict__ sp) {
    int idx = blockIdx.x * 256 + threadIdx.x;
    float I = 0.f;
#pragma unroll
    for (int s = 0; s < 8; s++) I += I3p[s * 8192 + idx];
    float m = vm[idx], s_ = vs[idx], p = sp[idx], spk;
    srm(m, s_, p, I, spk);
    vm[idx] = m; vs[idx] = s_; sp[idx] = spk;
}

// ============ fc4 + srm4 + accumulate ============
__global__ __launch_bounds__(256) void k_fc4(const float* __restrict__ sp3,
                                             const float* __restrict__ W4,
                                             float* __restrict__ vm, float* __restrict__ vs,
                                             float* __restrict__ sp, float* __restrict__ out) {
    int tid = threadIdx.x;
    if (tid >= N4) return;
    int b = tid / 11, o = tid - b * 11;
    const float* a = sp3 + b * 512;
    const float* w = W4 + o * 512;
    float acc = 0.f;
    for (int k = 0; k < 512; k++) acc += a[k] * w[k];
    float m = vm[tid], s = vs[tid], p = sp[tid], spk;
    srm(m, s, p, acc, spk);
    vm[tid] = m; vs[tid] = s; sp[tid] = spk;
    out[tid] += spk * 0.0625f;
}

extern "C" void kernel_launch(void* const* d_in, const int* in_sizes, int n_in,
                              void* d_out, int out_size, void* d_ws, size_t ws_size,
                              hipStream_t stream) {
    const float* in = (const float*)d_in[0];
    const float* W0 = (const float*)d_in[1];
    const float* W1 = (const float*)d_in[2];
    const float* W2 = (const float*)d_in[3];
    const float* W3 = (const float*)d_in[4];
    const float* W4 = (const float*)d_in[5];
    float* out = (float*)d_out;
    float* ws = (float*)d_ws;

    size_t off = 0;
    auto alloc = [&](size_t n) { float* p = ws + off; off += n; return p; };
    float *vm0 = alloc(N0), *vs0 = alloc(N0), *sp0 = alloc(N0);
    float *vm1 = alloc(N1), *vs1 = alloc(N1), *sp1 = alloc(N1);
    float *vm2 = alloc(N2), *vs2 = alloc(N2), *sp2 = alloc(N2);
    float *vm3 = alloc(N3), *vs3 = alloc(N3), *sp3 = alloc(N3);
    float *vm4 = alloc(N4), *vs4 = alloc(N4), *sp4 = alloc(N4);
    size_t state_bytes = off * sizeof(float);
    float *p1 = alloc(N2), *p2 = alloc(P2N), *I3p = alloc(I3PN);

    hipMemsetAsync(d_ws, 0, state_bytes, stream);
    hipMemsetAsync(d_out, 0, N4 * sizeof(float), stream);

    for (int t = 0; t < T; t++) {
        k_conv0<<<B * 4 * 8, 256, 0, stream>>>(in, W0, vm0, vs0, sp0, t);
        k_conv1<<<B * 4 * 16, 256, 0, stream>>>(sp0, W1, vm1, vs1, sp1, p1);
        k_conv2<<<B * 16, 256, 0, stream>>>(p1, W2, vm2, vs2, sp2, p2);
        k_fc3<<<256, 256, 0, stream>>>(p2, W3, I3p);
        k_srm3<<<N3 / 256, 256, 0, stream>>>(I3p, vm3, vs3, sp3);
        k_fc4<<<1, 256, 0, stream>>>(sp3, W4, vm4, vs4, sp4, out);
    }
}

// Round 3
// 9866.549 us; speedup vs baseline: 1.7759x; 1.2996x over previous
//
#include <hip/hip_runtime.h>

// SRM constants (match reference: float(np.exp(-1/16)), float(np.exp(-1/4)))
#define DM 0.9394130628134758f
#define DSC 0.7788007830714049f
#define TH 0.3f

#define B 16
#define T 16

#define N0 (16*64*64*64)
#define N1 (16*128*64*64)
#define N2 (16*128*32*32)
#define N3 (16*512)
#define N4 (16*11)
#define P2N (16*32768)
#define KS3 16
#define I3PN (KS3*8192)

__device__ __forceinline__ void srm(float& m, float& s, float p, float I, float& spk) {
    m = DM * m * (1.f - p) + I;
    s = DSC * s * (1.f - p) + I;
    spk = (m - s > TH) ? 1.f : 0.f;
}

// ============ conv0: [B,2,64,64](clip) -> [B,64,64,64] + SRM ============
// grid: B*4yt*8cog = 512 blocks, 256 thr, 16 rows x 64 cols x 8 co.
#define S0 68
__global__ __launch_bounds__(256) void k_conv0(const float* __restrict__ in,
                                               const float* __restrict__ W0,
                                               float* __restrict__ vm, float* __restrict__ vs,
                                               float* __restrict__ sp, int t) {
    __shared__ float tile[2][18 * S0];
    int bid = blockIdx.x;
    int cog = bid & 7, yt = (bid >> 3) & 3, b = bid >> 5;
    int tid = threadIdx.x;
    int tx = (tid & 15) * 4, ty = tid >> 4, y0 = yt * 16;

    for (int cl = 0; cl < 2; cl++) {
        const float* src = in + ((size_t)((b * T + t) * 2 + cl)) * 4096;
        for (int i = tid; i < 18 * 66; i += 256) {
            int r = i / 66, c = i - r * 66;
            int gy = y0 + r - 1, gx = c - 1;
            float v = 0.f;
            if ((unsigned)gy < 64u && (unsigned)gx < 64u)
                v = fminf(fmaxf(src[gy * 64 + gx], 0.f), 1.f);
            tile[cl][r * S0 + c] = v;
        }
    }
    __syncthreads();

    float acc[8][4] = {};
#pragma unroll
    for (int cl = 0; cl < 2; cl++) {
        const float* wb = W0 + ((size_t)cog * 8 * 2 + cl) * 9;
#pragma unroll
        for (int dy = 0; dy < 3; dy++) {
            float4 A = *(const float4*)&tile[cl][(ty + dy) * S0 + tx];
            float4 Bv = *(const float4*)&tile[cl][(ty + dy) * S0 + tx + 4];
            float r0 = A.x, r1 = A.y, r2 = A.z, r3 = A.w, r4 = Bv.x, r5 = Bv.y;
#pragma unroll
            for (int c = 0; c < 8; c++) {
                const float* w = wb + (size_t)c * 2 * 9 + dy * 3;
                float wa = w[0], wbx = w[1], wc = w[2];
                acc[c][0] += wa * r0 + wbx * r1 + wc * r2;
                acc[c][1] += wa * r1 + wbx * r2 + wc * r3;
                acc[c][2] += wa * r2 + wbx * r3 + wc * r4;
                acc[c][3] += wa * r3 + wbx * r4 + wc * r5;
            }
        }
    }

    int y = y0 + ty;
#pragma unroll
    for (int c = 0; c < 8; c++) {
        int co = cog * 8 + c;
        size_t obase = (((size_t)b * 64 + co) * 64 + y) * 64 + tx;
        float4 m4 = *(float4*)&vm[obase];
        float4 s4 = *(float4*)&vs[obase];
        float4 p4 = *(float4*)&sp[obase];
        float k0, k1, k2, k3;
        srm(m4.x, s4.x, p4.x, acc[c][0], k0);
        srm(m4.y, s4.y, p4.y, acc[c][1], k1);
        srm(m4.z, s4.z, p4.z, acc[c][2], k2);
        srm(m4.w, s4.w, p4.w, acc[c][3], k3);
        *(float4*)&vm[obase] = m4;
        *(float4*)&vs[obase] = s4;
        *(float4*)&sp[obase] = make_float4(k0, k1, k2, k3);
    }
}

// ============ conv1: [B,64,64,64] -> [B,128,64,64] + SRM + fused pool1 ============
// grid: B*8yt*16cog = 2048 blocks, 128 thr. Block: 8 rows x 64 cols x 8 co.
// ci chunks of 4 (LDS 10.9KB) -> 8 blocks/CU, 16 waves/CU.
#define S1 68
__global__ __launch_bounds__(128) void k_conv1(const float* __restrict__ s0,
                                               const float* __restrict__ W1,
                                               float* __restrict__ vm, float* __restrict__ vs,
                                               float* __restrict__ sp, float* __restrict__ p1) {
    __shared__ float tile[4][10 * S1];
    int bid = blockIdx.x;
    int cog = bid & 15, yt = (bid >> 4) & 7, b = bid >> 7;
    int tid = threadIdx.x;
    int tx = (tid & 15) * 4, ty = tid >> 4;     // ty 0..7
    int y0 = yt * 8;

    float acc[8][4] = {};
    for (int ch = 0; ch < 16; ch++) {
        for (int cl = 0; cl < 4; cl++) {
            const float* src = s0 + ((size_t)(b * 64 + ch * 4 + cl)) * 4096;
            for (int i = tid; i < 660; i += 128) {
                int r = i / 66, c = i - r * 66;
                int gy = y0 + r - 1, gx = c - 1;
                float v = 0.f;
                if ((unsigned)gy < 64u && (unsigned)gx < 64u) v = src[gy * 64 + gx];
                tile[cl][r * S1 + c] = v;
            }
        }
        __syncthreads();
        for (int cl = 0; cl < 4; cl++) {
            int ci = ch * 4 + cl;
            const float* wb = W1 + ((size_t)cog * 8 * 64 + ci) * 9;
#pragma unroll
            for (int dy = 0; dy < 3; dy++) {
                float4 A = *(const float4*)&tile[cl][(ty + dy) * S1 + tx];
                float4 Bv = *(const float4*)&tile[cl][(ty + dy) * S1 + tx + 4];
                float r0 = A.x, r1 = A.y, r2 = A.z, r3 = A.w, r4 = Bv.x, r5 = Bv.y;
#pragma unroll
                for (int c = 0; c < 8; c++) {
                    const float* w = wb + (size_t)c * 64 * 9 + dy * 3;
                    float wa = w[0], wbx = w[1], wc = w[2];
                    acc[c][0] += wa * r0 + wbx * r1 + wc * r2;
                    acc[c][1] += wa * r1 + wbx * r2 + wc * r3;
                    acc[c][2] += wa * r2 + wbx * r3 + wc * r4;
                    acc[c][3] += wa * r3 + wbx * r4 + wc * r5;
                }
            }
        }
        __syncthreads();
    }

    int y = y0 + ty;
#pragma unroll
    for (int c = 0; c < 8; c++) {
        int co = cog * 8 + c;
        size_t obase = (((size_t)b * 128 + co) * 64 + y) * 64 + tx;
        float4 m4 = *(float4*)&vm[obase];
        float4 s4 = *(float4*)&vs[obase];
        float4 p4 = *(float4*)&sp[obase];
        float k0, k1, k2, k3;
        srm(m4.x, s4.x, p4.x, acc[c][0], k0);
        srm(m4.y, s4.y, p4.y, acc[c][1], k1);
        srm(m4.z, s4.z, p4.z, acc[c][2], k2);
        srm(m4.w, s4.w, p4.w, acc[c][3], k3);
        *(float4*)&vm[obase] = m4;
        *(float4*)&vs[obase] = s4;
        *(float4*)&sp[obase] = make_float4(k0, k1, k2, k3);
        // fused maxpool 2x2: horiz in-thread, vert via lane^16 (ty^1)
        float h0 = fmaxf(k0, k1), h1 = fmaxf(k2, k3);
        float g0 = __shfl_xor(h0, 16);
        float g1 = __shfl_xor(h1, 16);
        if (!(ty & 1)) {
            float2 pv = make_float2(fmaxf(h0, g0), fmaxf(h1, g1));
            *(float2*)&p1[(((size_t)b * 128 + co) * 32 + (y >> 1)) * 32 + (tx >> 1)] = pv;
        }
    }
}

// ============ conv2: [B,128,32,32] -> [B,128,32,32] + SRM + fused pool2 ============
// grid: B*4yt*16cog = 1024 blocks, 256 thr. Block: 8 rows x 32 cols x 8 co,
// 1 px/thread, acc[8]. ci chunks of 16 (LDS 23KB).
#define S2 36
__global__ __launch_bounds__(256) void k_conv2(const float* __restrict__ p1,
                                               const float* __restrict__ W2,
                                               float* __restrict__ vm, float* __restrict__ vs,
                                               float* __restrict__ sp, float* __restrict__ p2) {
    __shared__ float tile[16][10 * S2];
    int bid = blockIdx.x;
    int cog = bid & 15, yt = (bid >> 4) & 3, b = bid >> 6;
    int tid = threadIdx.x;
    int tx = tid & 31, ty = tid >> 5;           // px = (yt*8+ty, tx)
    int y0 = yt * 8;

    float acc[8] = {};
    for (int ch = 0; ch < 8; ch++) {
        for (int cl = 0; cl < 16; cl++) {
            const float* src = p1 + ((size_t)(b * 128 + ch * 16 + cl)) * 1024;
            for (int i = tid; i < 340; i += 256) {
                int r = i / 34, c = i - r * 34;
                int gy = y0 + r - 1, gx = c - 1;
                float v = 0.f;
                if ((unsigned)gy < 32u && (unsigned)gx < 32u) v = src[gy * 32 + gx];
                tile[cl][r * S2 + c] = v;
            }
        }
        __syncthreads();
        for (int cl = 0; cl < 16; cl++) {
            int ci = ch * 16 + cl;
            const float* wb = W2 + ((size_t)cog * 8 * 128 + ci) * 9;
#pragma unroll
            for (int dy = 0; dy < 3; dy++) {
                float r0 = tile[cl][(ty + dy) * S2 + tx];
                float r1 = tile[cl][(ty + dy) * S2 + tx + 1];
                float r2 = tile[cl][(ty + dy) * S2 + tx + 2];
#pragma unroll
                for (int c = 0; c < 8; c++) {
                    const float* w = wb + (size_t)c * 128 * 9 + dy * 3;
                    acc[c] += w[0] * r0 + w[1] * r1 + w[2] * r2;
                }
            }
        }
        __syncthreads();
    }

    int y = y0 + ty;
#pragma unroll
    for (int c = 0; c < 8; c++) {
        int co = cog * 8 + c;
        size_t o = (((size_t)b * 128 + co) * 32 + y) * 32 + tx;
        float m = vm[o], s = vs[o], p = sp[o], spk;
        srm(m, s, p, acc[c], spk);
        vm[o] = m; vs[o] = s; sp[o] = spk;
        // fused maxpool 2x2 -> p2 [b][co][16][16]
        float hx = fmaxf(spk, __shfl_xor(spk, 1));    // cols pair (tx^1)
        float v = fmaxf(hx, __shfl_xor(hx, 32));      // rows pair (ty^1)
        if (!(tx & 1) && !(ty & 1))
            p2[(size_t)b * 32768 + co * 256 + (y >> 1) * 16 + (tx >> 1)] = v;
    }
}

// ============ fc3 partial: p2[16,32768] @ W3^T -> I3p[KS3][16][512] ============
// grid 512 = 32 ot x 16 ks; block 256 = 16 o x 16 b
__global__ __launch_bounds__(256) void k_fc3(const float* __restrict__ p2,
                                             const float* __restrict__ W3,
                                             float* __restrict__ I3p) {
    int ot = blockIdx.x & 31, ks = blockIdx.x >> 5;
    int b = threadIdx.x & 15, o = ot * 16 + (threadIdx.x >> 4);
    const float4* w4 = (const float4*)(W3 + (size_t)o * 32768 + ks * 2048);
    const float4* p4 = (const float4*)(p2 + (size_t)b * 32768 + ks * 2048);
    float acc = 0.f;
    for (int k = 0; k < 512; k++) {
        float4 a = w4[k], c = p4[k];
        acc += a.x * c.x + a.y * c.y + a.z * c.z + a.w * c.w;
    }
    I3p[ks * 8192 + b * 512 + o] = acc;
}

// ============ srm3: reduce KS3 partials + SRM -> sp3 [16,512] ============
__global__ __launch_bounds__(256) void k_srm3(const float* __restrict__ I3p,
                                              float* __restrict__ vm, float* __restrict__ vs,
                                              float* __restrict__ sp) {
    int idx = blockIdx.x * 256 + threadIdx.x;
    float I = 0.f;
#pragma unroll
    for (int s = 0; s < KS3; s++) I += I3p[s * 8192 + idx];
    float m = vm[idx], s_ = vs[idx], p = sp[idx], spk;
    srm(m, s_, p, I, spk);
    vm[idx] = m; vs[idx] = s_; sp[idx] = spk;
}

// ============ fc4 + srm4 + accumulate ============
__global__ __launch_bounds__(256) void k_fc4(const float* __restrict__ sp3,
                                             const float* __restrict__ W4,
                                             float* __restrict__ vm, float* __restrict__ vs,
                                             float* __restrict__ sp, float* __restrict__ out) {
    int tid = threadIdx.x;
    if (tid >= N4) return;
    int b = tid / 11, o = tid - b * 11;
    const float4* a = (const float4*)(sp3 + b * 512);
    const float4* w = (const float4*)(W4 + o * 512);
    float acc = 0.f;
    for (int k = 0; k < 128; k++) {
        float4 x = a[k], y = w[k];
        acc += x.x * y.x + x.y * y.y + x.z * y.z + x.w * y.w;
    }
    float m = vm[tid], s = vs[tid], p = sp[tid], spk;
    srm(m, s, p, acc, spk);
    vm[tid] = m; vs[tid] = s; sp[tid] = spk;
    out[tid] += spk * 0.0625f;
}

extern "C" void kernel_launch(void* const* d_in, const int* in_sizes, int n_in,
                              void* d_out, int out_size, void* d_ws, size_t ws_size,
                              hipStream_t stream) {
    const float* in = (const float*)d_in[0];
    const float* W0 = (const float*)d_in[1];
    const float* W1 = (const float*)d_in[2];
    const float* W2 = (const float*)d_in[3];
    const float* W3 = (const float*)d_in[4];
    const float* W4 = (const float*)d_in[5];
    float* out = (float*)d_out;
    float* ws = (float*)d_ws;

    size_t off = 0;
    auto alloc = [&](size_t n) { float* p = ws + off; off += n; return p; };
    float *vm0 = alloc(N0), *vs0 = alloc(N0), *sp0 = alloc(N0);
    float *vm1 = alloc(N1), *vs1 = alloc(N1), *sp1 = alloc(N1);
    float *vm2 = alloc(N2), *vs2 = alloc(N2), *sp2 = alloc(N2);
    float *vm3 = alloc(N3), *vs3 = alloc(N3), *sp3 = alloc(N3);
    float *vm4 = alloc(N4), *vs4 = alloc(N4), *sp4 = alloc(N4);
    size_t state_bytes = off * sizeof(float);
    float *p1 = alloc(N2), *p2 = alloc(P2N), *I3p = alloc(I3PN);

    hipMemsetAsync(d_ws, 0, state_bytes, stream);
    hipMemsetAsync(d_out, 0, N4 * sizeof(float), stream);

    for (int t = 0; t < T; t++) {
        k_conv0<<<B * 4 * 8, 256, 0, stream>>>(in, W0, vm0, vs0, sp0, t);
        k_conv1<<<B * 8 * 16, 128, 0, stream>>>(sp0, W1, vm1, vs1, sp1, p1);
        k_conv2<<<B * 4 * 16, 256, 0, stream>>>(p1, W2, vm2, vs2, sp2, p2);
        k_fc3<<<32 * KS3, 256, 0, stream>>>(p2, W3, I3p);
        k_srm3<<<N3 / 256, 256, 0, stream>>>(I3p, vm3, vs3, sp3);
        k_fc4<<<1, 256, 0, stream>>>(sp3, W4, vm4, vs4, sp4, out);
    }
}

// Round 4
// 6061.290 us; speedup vs baseline: 2.8907x; 1.6278x over previous
//
#include <hip/hip_runtime.h>
#include <hip/hip_bf16.h>

// SRM constants (match reference: float(np.exp(-1/16)), float(np.exp(-1/4)))
#define DM 0.9394130628134758f
#define DSC 0.7788007830714049f
#define TH 0.3f

#define B 16
#define T 16

#define N0 (16*64*64*64)
#define N1 (16*128*64*64)
#define N2 (16*128*32*32)
#define N3 (16*512)
#define N4 (16*11)
#define P2N (16*32768)
#define KS3 16
#define I3PN (KS3*8192)

typedef short short8 __attribute__((ext_vector_type(8)));
typedef float f32x4 __attribute__((ext_vector_type(4)));

#define SPK1 ((unsigned short)0x3F80)  // bf16 1.0

__device__ __forceinline__ void srm(float& m, float& s, float p, float I, float& spk) {
    m = DM * m * (1.f - p) + I;
    s = DSC * s * (1.f - p) + I;
    spk = (m - s > TH) ? 1.f : 0.f;
}

// ============ weight prep: fp32 OIHW -> 3-term bf16 [term][tap][co][ci] ============
__global__ __launch_bounds__(256) void k_prep(const float* __restrict__ W,
                                              unsigned short* __restrict__ Ws,
                                              int CO, int CI) {
    int idx = blockIdx.x * 256 + threadIdx.x;
    int total = CO * CI * 9;
    if (idx >= total) return;
    int tap = idx % 9, tmp = idx / 9, ci = tmp % CI, co = tmp / CI;
    float w = W[((size_t)co * CI + ci) * 9 + tap];
    __hip_bfloat16 h = __float2bfloat16(w);
    float hf = __bfloat162float(h);
    __hip_bfloat16 mdd = __float2bfloat16(w - hf);
    float mf = __bfloat162float(mdd);
    __hip_bfloat16 lo = __float2bfloat16(w - hf - mf);
    size_t base = ((size_t)tap * CO + co) * CI + ci;
    size_t stride = (size_t)9 * CO * CI;
    Ws[base] = *(unsigned short*)&h;
    Ws[base + stride] = *(unsigned short*)&mdd;
    Ws[base + 2 * stride] = *(unsigned short*)&lo;
}

// ============ conv0: [B,2,64,64](clip) -> SRM state (NCHW fp32) + s0b (NHWC bf16) ============
// grid: B*8yt*8cog = 1024 blocks, 128 thr. 8 rows x 64 cols x 8 co.
#define S0 68
__global__ __launch_bounds__(128) void k_conv0(const float* __restrict__ in,
                                               const float* __restrict__ W0,
                                               float* __restrict__ vm, float* __restrict__ vs,
                                               float* __restrict__ sp,
                                               unsigned short* __restrict__ s0b, int t) {
    __shared__ float tile[2][10 * S0];
    int bid = blockIdx.x;
    int cog = bid & 7, yt = (bid >> 3) & 7, b = bid >> 6;
    int tid = threadIdx.x;
    int tx = (tid & 15) * 4, ty = tid >> 4;  // ty 0..7
    int y0 = yt * 8;

    for (int i = tid; i < 2 * 660; i += 128) {
        int cl = i / 660, rem = i - cl * 660;
        int r = rem / 66, c = rem - r * 66;
        int gy = y0 + r - 1, gx = c - 1;
        float v = 0.f;
        if ((unsigned)gy < 64u && (unsigned)gx < 64u) {
            const float* src = in + ((size_t)((b * T + t) * 2 + cl)) * 4096;
            v = fminf(fmaxf(src[gy * 64 + gx], 0.f), 1.f);
        }
        tile[cl][r * S0 + c] = v;
    }
    __syncthreads();

    float acc[8][4] = {};
#pragma unroll
    for (int cl = 0; cl < 2; cl++) {
        const float* wb = W0 + ((size_t)cog * 8 * 2 + cl) * 9;
#pragma unroll
        for (int dy = 0; dy < 3; dy++) {
            float4 A = *(const float4*)&tile[cl][(ty + dy) * S0 + tx];
            float4 Bv = *(const float4*)&tile[cl][(ty + dy) * S0 + tx + 4];
            float r0 = A.x, r1 = A.y, r2 = A.z, r3 = A.w, r4 = Bv.x, r5 = Bv.y;
#pragma unroll
            for (int c = 0; c < 8; c++) {
                const float* w = wb + (size_t)c * 2 * 9 + dy * 3;
                float wa = w[0], wbx = w[1], wc = w[2];
                acc[c][0] += wa * r0 + wbx * r1 + wc * r2;
                acc[c][1] += wa * r1 + wbx * r2 + wc * r3;
                acc[c][2] += wa * r2 + wbx * r3 + wc * r4;
                acc[c][3] += wa * r3 + wbx * r4 + wc * r5;
            }
        }
    }

    int y = y0 + ty;
    unsigned short* s0p = s0b + (size_t)b * 64 * 64 * 64;
#pragma unroll
    for (int c = 0; c < 8; c++) {
        int co = cog * 8 + c;
        size_t obase = (((size_t)b * 64 + co) * 64 + y) * 64 + tx;
        float4 m4 = *(float4*)&vm[obase];
        float4 s4 = *(float4*)&vs[obase];
        float4 p4 = *(float4*)&sp[obase];
        float k0, k1, k2, k3;
        srm(m4.x, s4.x, p4.x, acc[c][0], k0);
        srm(m4.y, s4.y, p4.y, acc[c][1], k1);
        srm(m4.z, s4.z, p4.z, acc[c][2], k2);
        srm(m4.w, s4.w, p4.w, acc[c][3], k3);
        *(float4*)&vm[obase] = m4;
        *(float4*)&vs[obase] = s4;
        *(float4*)&sp[obase] = make_float4(k0, k1, k2, k3);
        s0p[((size_t)(y * 64 + tx + 0)) * 64 + co] = k0 > 0.5f ? SPK1 : 0;
        s0p[((size_t)(y * 64 + tx + 1)) * 64 + co] = k1 > 0.5f ? SPK1 : 0;
        s0p[((size_t)(y * 64 + tx + 2)) * 64 + co] = k2 > 0.5f ? SPK1 : 0;
        s0p[((size_t)(y * 64 + tx + 3)) * 64 + co] = k3 > 0.5f ? SPK1 : 0;
    }
}

// ============ conv1 MFMA: s0b[b][64][64][64] bf16 -> SRM(NHWC) + sp1b ============
// grid: 16b*64y = 1024 blocks, 256 thr (4 waves). Wave: co-tile 32 (2 nt), x 0..63 (4 xt).
__global__ __launch_bounds__(256) void k_conv1(const unsigned short* __restrict__ s0b,
                                               const unsigned short* __restrict__ W1s,
                                               float* __restrict__ mvs1,
                                               unsigned short* __restrict__ sp1b) {
    int y = blockIdx.x & 63, b = blockIdx.x >> 6;
    int lane = threadIdx.x & 63, wv = threadIdx.x >> 6;
    int n = lane & 15, q = lane >> 4;
    int cobase = wv * 32;
    const unsigned short* s0p = s0b + (size_t)b * 64 * 64 * 64;

    f32x4 acc[4][2];
#pragma unroll
    for (int i = 0; i < 4; i++)
#pragma unroll
        for (int j = 0; j < 2; j++) acc[i][j] = (f32x4){0.f, 0.f, 0.f, 0.f};

    const short8 zf = {0, 0, 0, 0, 0, 0, 0, 0};
#pragma unroll
    for (int kc = 0; kc < 2; kc++) {
        int cio = kc * 32 + q * 8;
#pragma unroll
        for (int dy = 0; dy < 3; dy++) {
            int gy = y + dy - 1;
            bool rok = (unsigned)gy < 64u;
            int gyc = min(max(gy, 0), 63);
#pragma unroll
            for (int dx = 0; dx < 3; dx++) {
                int tap = dy * 3 + dx;
                short8 Bf[2][3];
#pragma unroll
                for (int nt = 0; nt < 2; nt++)
#pragma unroll
                    for (int tm = 0; tm < 3; tm++)
                        Bf[nt][tm] = *(const short8*)(W1s +
                            (((size_t)tm * 9 + tap) * 128 + cobase + nt * 16 + n) * 64 + cio);
#pragma unroll
                for (int xt = 0; xt < 4; xt++) {
                    int gx = xt * 16 + n + dx - 1;
                    bool ok = rok && ((unsigned)gx < 64u);
                    int gxc = min(max(gx, 0), 63);
                    short8 Af = *(const short8*)(s0p + ((size_t)(gyc * 64 + gxc)) * 64 + cio);
                    Af = ok ? Af : zf;
#pragma unroll
                    for (int nt = 0; nt < 2; nt++)
#pragma unroll
                        for (int tm = 0; tm < 3; tm++)
                            acc[xt][nt] = __builtin_amdgcn_mfma_f32_16x16x32_bf16(
                                Af, Bf[nt][tm], acc[xt][nt], 0, 0, 0);
                }
            }
        }
    }

    size_t base_b = (size_t)b * 64 * 64 * 128;
#pragma unroll
    for (int xt = 0; xt < 4; xt++)
#pragma unroll
        for (int nt = 0; nt < 2; nt++) {
            int co = cobase + nt * 16 + n;
            int x0 = xt * 16 + q * 4;
#pragma unroll
            for (int r = 0; r < 4; r++) {
                size_t pos = base_b + ((size_t)(y * 64 + x0 + r)) * 128 + co;
                float2 mv = *(float2*)&mvs1[pos * 2];
                float pprev = sp1b[pos] ? 1.f : 0.f;
                float m = mv.x, s = mv.y, spk;
                srm(m, s, pprev, acc[xt][nt][r], spk);
                *(float2*)&mvs1[pos * 2] = make_float2(m, s);
                sp1b[pos] = spk > 0.5f ? SPK1 : 0;
            }
        }
}

// ============ pool1: sp1b [b][64][64][128] -> p1b [b][32][32][128] (bf16) ============
__global__ __launch_bounds__(256) void k_pool1(const unsigned short* __restrict__ sp1b,
                                               unsigned short* __restrict__ p1b) {
    int idx = blockIdx.x * 256 + threadIdx.x;   // 16*32*32*16 = 262144
    int c8 = idx & 15, x = (idx >> 4) & 31, y = (idx >> 9) & 31, b = idx >> 14;
    int c0 = c8 * 8;
    const unsigned short* sb = sp1b + (size_t)b * 64 * 64 * 128;
    const unsigned short* a0 = sb + ((size_t)(2 * y) * 64 + 2 * x) * 128 + c0;
    const unsigned short* a1 = a0 + 128;
    const unsigned short* a2 = a0 + 64 * 128;
    const unsigned short* a3 = a2 + 128;
    unsigned short o[8];
#pragma unroll
    for (int j = 0; j < 8; j++) {
        unsigned short v = a0[j];
        v = max(v, a1[j]); v = max(v, a2[j]); v = max(v, a3[j]);
        o[j] = v;
    }
    unsigned short* dst = p1b + ((size_t)b * 32 * 32 + y * 32 + x) * 128 + c0;
#pragma unroll
    for (int j = 0; j < 8; j++) dst[j] = o[j];
}

// ============ conv2 MFMA: p1b[b][32][32][128] -> SRM(NHWC) + sp2b ============
// grid: 16b*32y = 512 blocks, 256 thr. Wave: co-tile 32, x 0..31 (2 xt), kc 0..3.
__global__ __launch_bounds__(256) void k_conv2(const unsigned short* __restrict__ p1b,
                                               const unsigned short* __restrict__ W2s,
                                               float* __restrict__ mvs2,
                                               unsigned short* __restrict__ sp2b) {
    int y = blockIdx.x & 31, b = blockIdx.x >> 5;
    int lane = threadIdx.x & 63, wv = threadIdx.x >> 6;
    int n = lane & 15, q = lane >> 4;
    int cobase = wv * 32;
    const unsigned short* sbp = p1b + (size_t)b * 32 * 32 * 128;

    f32x4 acc[2][2];
#pragma unroll
    for (int i = 0; i < 2; i++)
#pragma unroll
        for (int j = 0; j < 2; j++) acc[i][j] = (f32x4){0.f, 0.f, 0.f, 0.f};

    const short8 zf = {0, 0, 0, 0, 0, 0, 0, 0};
    for (int kc = 0; kc < 4; kc++) {
        int cio = kc * 32 + q * 8;
#pragma unroll
        for (int dy = 0; dy < 3; dy++) {
            int gy = y + dy - 1;
            bool rok = (unsigned)gy < 32u;
            int gyc = min(max(gy, 0), 31);
#pragma unroll
            for (int dx = 0; dx < 3; dx++) {
                int tap = dy * 3 + dx;
                short8 Bf[2][3];
#pragma unroll
                for (int nt = 0; nt < 2; nt++)
#pragma unroll
                    for (int tm = 0; tm < 3; tm++)
                        Bf[nt][tm] = *(const short8*)(W2s +
                            (((size_t)tm * 9 + tap) * 128 + cobase + nt * 16 + n) * 128 + cio);
#pragma unroll
                for (int xt = 0; xt < 2; xt++) {
                    int gx = xt * 16 + n + dx - 1;
                    bool ok = rok && ((unsigned)gx < 32u);
                    int gxc = min(max(gx, 0), 31);
                    short8 Af = *(const short8*)(sbp + ((size_t)(gyc * 32 + gxc)) * 128 + cio);
                    Af = ok ? Af : zf;
#pragma unroll
                    for (int nt = 0; nt < 2; nt++)
#pragma unroll
                        for (int tm = 0; tm < 3; tm++)
                            acc[xt][nt] = __builtin_amdgcn_mfma_f32_16x16x32_bf16(
                                Af, Bf[nt][tm], acc[xt][nt], 0, 0, 0);
                }
            }
        }
    }

    size_t base_b = (size_t)b * 32 * 32 * 128;
#pragma unroll
    for (int xt = 0; xt < 2; xt++)
#pragma unroll
        for (int nt = 0; nt < 2; nt++) {
            int co = cobase + nt * 16 + n;
            int x0 = xt * 16 + q * 4;
#pragma unroll
            for (int r = 0; r < 4; r++) {
                size_t pos = base_b + ((size_t)(y * 32 + x0 + r)) * 128 + co;
                float2 mv = *(float2*)&mvs2[pos * 2];
                float pprev = sp2b[pos] ? 1.f : 0.f;
                float m = mv.x, s = mv.y, spk;
                srm(m, s, pprev, acc[xt][nt][r], spk);
                *(float2*)&mvs2[pos * 2] = make_float2(m, s);
                sp2b[pos] = spk > 0.5f ? SPK1 : 0;
            }
        }
}

// ============ pool2: sp2b [b][32][32][128] -> p2 fp32 NCHW flat [b][32768] ============
__global__ __launch_bounds__(256) void k_pool2(const unsigned short* __restrict__ sp2b,
                                               float* __restrict__ p2) {
    int idx = blockIdx.x * 256 + threadIdx.x;   // 16*16*16*16 = 65536
    int c8 = idx & 15, x = (idx >> 4) & 15, y = (idx >> 8) & 15, b = idx >> 12;
    int c0 = c8 * 8;
    const unsigned short* sb = sp2b + (size_t)b * 32 * 32 * 128;
    const unsigned short* a0 = sb + ((size_t)(2 * y) * 32 + 2 * x) * 128 + c0;
    const unsigned short* a1 = a0 + 128;
    const unsigned short* a2 = a0 + 32 * 128;
    const unsigned short* a3 = a2 + 128;
    float* dst = p2 + (size_t)b * 32768 + y * 16 + x;
#pragma unroll
    for (int j = 0; j < 8; j++) {
        unsigned short v = a0[j];
        v = max(v, a1[j]); v = max(v, a2[j]); v = max(v, a3[j]);
        dst[(size_t)(c0 + j) * 256] = v ? 1.f : 0.f;
    }
}

// ============ fc3 partial: p2[16,32768] @ W3^T -> I3p[KS3][16][512] ============
__global__ __launch_bounds__(256) void k_fc3(const float* __restrict__ p2,
                                             const float* __restrict__ W3,
                                             float* __restrict__ I3p) {
    int ot = blockIdx.x & 31, ks = blockIdx.x >> 5;
    int b = threadIdx.x & 15, o = ot * 16 + (threadIdx.x >> 4);
    const float4* w4 = (const float4*)(W3 + (size_t)o * 32768 + ks * 2048);
    const float4* p4 = (const float4*)(p2 + (size_t)b * 32768 + ks * 2048);
    float acc = 0.f;
    for (int k = 0; k < 512; k++) {
        float4 a = w4[k], c = p4[k];
        acc += a.x * c.x + a.y * c.y + a.z * c.z + a.w * c.w;
    }
    I3p[ks * 8192 + b * 512 + o] = acc;
}

// ============ srm3 ============
__global__ __launch_bounds__(256) void k_srm3(const float* __restrict__ I3p,
                                              float* __restrict__ vm, float* __restrict__ vs,
                                              float* __restrict__ sp) {
    int idx = blockIdx.x * 256 + threadIdx.x;
    float I = 0.f;
#pragma unroll
    for (int s = 0; s < KS3; s++) I += I3p[s * 8192 + idx];
    float m = vm[idx], s_ = vs[idx], p = sp[idx], spk;
    srm(m, s_, p, I, spk);
    vm[idx] = m; vs[idx] = s_; sp[idx] = spk;
}

// ============ fc4 + srm4 + accumulate ============
__global__ __launch_bounds__(256) void k_fc4(const float* __restrict__ sp3,
                                             const float* __restrict__ W4,
                                             float* __restrict__ vm, float* __restrict__ vs,
                                             float* __restrict__ sp, float* __restrict__ out) {
    int tid = threadIdx.x;
    if (tid >= N4) return;
    int b = tid / 11, o = tid - b * 11;
    const float4* a = (const float4*)(sp3 + b * 512);
    const float4* w = (const float4*)(W4 + o * 512);
    float acc = 0.f;
    for (int k = 0; k < 128; k++) {
        float4 x = a[k], y = w[k];
        acc += x.x * y.x + x.y * y.y + x.z * y.z + x.w * y.w;
    }
    float m = vm[tid], s = vs[tid], p = sp[tid], spk;
    srm(m, s, p, acc, spk);
    vm[tid] = m; vs[tid] = s; sp[tid] = spk;
    out[tid] += spk * 0.0625f;
}

extern "C" void kernel_launch(void* const* d_in, const int* in_sizes, int n_in,
                              void* d_out, int out_size, void* d_ws, size_t ws_size,
                              hipStream_t stream) {
    const float* in = (const float*)d_in[0];
    const float* W0 = (const float*)d_in[1];
    const float* W1 = (const float*)d_in[2];
    const float* W2 = (const float*)d_in[3];
    const float* W3 = (const float*)d_in[4];
    const float* W4 = (const float*)d_in[5];
    float* out = (float*)d_out;
    char* ws = (char*)d_ws;

    size_t off = 0;
    auto allocf = [&](size_t n) { float* p = (float*)(ws + off); off += n * 4; return p; };
    auto allocu = [&](size_t n) { unsigned short* p = (unsigned short*)(ws + off); off += n * 2; return p; };

    // ---- zero-init region (SRM state) ----
    float* vm0 = allocf(N0); float* vs0 = allocf(N0); float* sp0 = allocf(N0);
    float* mvs1 = allocf((size_t)N1 * 2);
    float* mvs2 = allocf((size_t)N2 * 2);
    float* vm3 = allocf(N3); float* vs3 = allocf(N3); float* sp3 = allocf(N3);
    float* vm4 = allocf(N4); float* vs4 = allocf(N4); float* sp4 = allocf(N4);
    unsigned short* sp1b = allocu(N1);
    unsigned short* sp2b = allocu(N2);
    size_t zbytes = off;

    // ---- scratch (fully rewritten each step) ----
    unsigned short* s0b = allocu(N0);
    unsigned short* p1b = allocu(N2);
    float* p2 = allocf(P2N);
    float* I3p = allocf(I3PN);
    unsigned short* W1s = allocu((size_t)3 * 9 * 128 * 64);
    unsigned short* W2s = allocu((size_t)3 * 9 * 128 * 128);

    hipMemsetAsync(d_ws, 0, zbytes, stream);
    hipMemsetAsync(d_out, 0, N4 * sizeof(float), stream);

    k_prep<<<(9 * 128 * 64 + 255) / 256, 256, 0, stream>>>(W1, W1s, 128, 64);
    k_prep<<<(9 * 128 * 128 + 255) / 256, 256, 0, stream>>>(W2, W2s, 128, 128);

    for (int t = 0; t < T; t++) {
        k_conv0<<<B * 8 * 8, 128, 0, stream>>>(in, W0, vm0, vs0, sp0, s0b, t);
        k_conv1<<<B * 64, 256, 0, stream>>>(s0b, W1s, mvs1, sp1b);
        k_pool1<<<262144 / 256, 256, 0, stream>>>(sp1b, p1b);
        k_conv2<<<B * 32, 256, 0, stream>>>(p1b, W2s, mvs2, sp2b);
        k_pool2<<<65536 / 256, 256, 0, stream>>>(sp2b, p2);
        k_fc3<<<32 * KS3, 256, 0, stream>>>(p2, W3, I3p);
        k_srm3<<<N3 / 256, 256, 0, stream>>>(I3p, vm3, vs3, sp3);
        k_fc4<<<1, 256, 0, stream>>>(sp3, W4, vm4, vs4, sp4, out);
    }
}

// Round 5
// 4453.739 us; speedup vs baseline: 3.9341x; 1.3609x over previous
//
#include <hip/hip_runtime.h>
#include <hip/hip_bf16.h>

// SRM constants (match reference: float(np.exp(-1/16)), float(np.exp(-1/4)))
#define DM 0.9394130628134758f
#define DSC 0.7788007830714049f
#define TH 0.3f

#define B 16
#define T 16

#define N0 (16*64*64*64)
#define N1 (16*128*64*64)
#define N2 (16*128*32*32)
#define N3 (16*512)
#define N4 (16*11)
#define P2N (16*32768)
#define KS3 16
#define I3PN (KS3*8192)

typedef short short8 __attribute__((ext_vector_type(8)));
typedef float f32x4 __attribute__((ext_vector_type(4)));

#define SPK1 ((unsigned short)0x3F80)  // bf16 1.0

__device__ __forceinline__ void srm(float& m, float& s, float p, float I, float& spk) {
    m = DM * m * (1.f - p) + I;
    s = DSC * s * (1.f - p) + I;
    spk = (m - s > TH) ? 1.f : 0.f;
}

// ============ weight prep: fp32 OIHW -> 3-term bf16 [term][tap][co][ci] ============
__global__ __launch_bounds__(256) void k_prep(const float* __restrict__ W,
                                              unsigned short* __restrict__ Ws,
                                              int CO, int CI) {
    int idx = blockIdx.x * 256 + threadIdx.x;
    int total = CO * CI * 9;
    if (idx >= total) return;
    int tap = idx % 9, tmp = idx / 9, ci = tmp % CI, co = tmp / CI;
    float w = W[((size_t)co * CI + ci) * 9 + tap];
    __hip_bfloat16 h = __float2bfloat16(w);
    float hf = __bfloat162float(h);
    __hip_bfloat16 mdd = __float2bfloat16(w - hf);
    float mf = __bfloat162float(mdd);
    __hip_bfloat16 lo = __float2bfloat16(w - hf - mf);
    size_t base = ((size_t)tap * CO + co) * CI + ci;
    size_t stride = (size_t)9 * CO * CI;
    Ws[base] = *(unsigned short*)&h;
    Ws[base + stride] = *(unsigned short*)&mdd;
    Ws[base + 2 * stride] = *(unsigned short*)&lo;
}

// ============ conv0: [B,2,64,64](clip) -> mvs0 (NCHW float2) + s0b (NHWC bf16) ============
// grid: B*8yt*8cog = 1024 blocks, 128 thr. 8 rows x 64 cols x 8 co.
// prev-spike is read from s0b (persists across steps; zero-initialized).
#define S0 68
__global__ __launch_bounds__(128) void k_conv0(const float* __restrict__ in,
                                               const float* __restrict__ W0,
                                               float* __restrict__ mvs0,
                                               unsigned short* __restrict__ s0b, int t) {
    __shared__ float tile[2][10 * S0];
    int bid = blockIdx.x;
    int cog = bid & 7, yt = (bid >> 3) & 7, b = bid >> 6;
    int tid = threadIdx.x;
    int tx = (tid & 15) * 4, ty = tid >> 4;  // ty 0..7
    int y0 = yt * 8;

    for (int i = tid; i < 2 * 660; i += 128) {
        int cl = i / 660, rem = i - cl * 660;
        int r = rem / 66, c = rem - r * 66;
        int gy = y0 + r - 1, gx = c - 1;
        float v = 0.f;
        if ((unsigned)gy < 64u && (unsigned)gx < 64u) {
            const float* src = in + ((size_t)((b * T + t) * 2 + cl)) * 4096;
            v = fminf(fmaxf(src[gy * 64 + gx], 0.f), 1.f);
        }
        tile[cl][r * S0 + c] = v;
    }
    __syncthreads();

    float acc[8][4] = {};
#pragma unroll
    for (int cl = 0; cl < 2; cl++) {
        const float* wb = W0 + ((size_t)cog * 8 * 2 + cl) * 9;
#pragma unroll
        for (int dy = 0; dy < 3; dy++) {
            float4 A = *(const float4*)&tile[cl][(ty + dy) * S0 + tx];
            float4 Bv = *(const float4*)&tile[cl][(ty + dy) * S0 + tx + 4];
            float r0 = A.x, r1 = A.y, r2 = A.z, r3 = A.w, r4 = Bv.x, r5 = Bv.y;
#pragma unroll
            for (int c = 0; c < 8; c++) {
                const float* w = wb + (size_t)c * 2 * 9 + dy * 3;
                float wa = w[0], wbx = w[1], wc = w[2];
                acc[c][0] += wa * r0 + wbx * r1 + wc * r2;
                acc[c][1] += wa * r1 + wbx * r2 + wc * r3;
                acc[c][2] += wa * r2 + wbx * r3 + wc * r4;
                acc[c][3] += wa * r3 + wbx * r4 + wc * r5;
            }
        }
    }

    int y = y0 + ty;
    unsigned short* s0p = s0b + (size_t)b * 64 * 64 * 64;
#pragma unroll
    for (int c = 0; c < 8; c++) {
        int co = cog * 8 + c;
        size_t obase = (((size_t)b * 64 + co) * 64 + y) * 64 + tx;
        float4 a01 = *(float4*)&mvs0[obase * 2];       // m0,s0,m1,s1
        float4 a23 = *(float4*)&mvs0[obase * 2 + 4];   // m2,s2,m3,s3
        size_t pb = ((size_t)(y * 64 + tx)) * 64 + co;
        float p0 = s0p[pb]         ? 1.f : 0.f;
        float p1 = s0p[pb + 64]    ? 1.f : 0.f;
        float p2 = s0p[pb + 128]   ? 1.f : 0.f;
        float p3 = s0p[pb + 192]   ? 1.f : 0.f;
        float k0, k1, k2, k3;
        srm(a01.x, a01.y, p0, acc[c][0], k0);
        srm(a01.z, a01.w, p1, acc[c][1], k1);
        srm(a23.x, a23.y, p2, acc[c][2], k2);
        srm(a23.z, a23.w, p3, acc[c][3], k3);
        *(float4*)&mvs0[obase * 2] = a01;
        *(float4*)&mvs0[obase * 2 + 4] = a23;
        s0p[pb]       = k0 > 0.5f ? SPK1 : 0;
        s0p[pb + 64]  = k1 > 0.5f ? SPK1 : 0;
        s0p[pb + 128] = k2 > 0.5f ? SPK1 : 0;
        s0p[pb + 192] = k3 > 0.5f ? SPK1 : 0;
    }
}

// ============ conv1 MFMA: s0b[b][64][64][64] bf16 -> SRM(NHWC) + sp1b ============
// grid: 16b*64y = 1024 blocks, 256 thr (4 waves). Wave: co-tile 32 (2 nt), x 0..63 (4 xt).
__global__ __launch_bounds__(256) void k_conv1(const unsigned short* __restrict__ s0b,
                                               const unsigned short* __restrict__ W1s,
                                               float* __restrict__ mvs1,
                                               unsigned short* __restrict__ sp1b) {
    int y = blockIdx.x & 63, b = blockIdx.x >> 6;
    int lane = threadIdx.x & 63, wv = threadIdx.x >> 6;
    int n = lane & 15, q = lane >> 4;
    int cobase = wv * 32;
    const unsigned short* s0p = s0b + (size_t)b * 64 * 64 * 64;

    f32x4 acc[4][2];
#pragma unroll
    for (int i = 0; i < 4; i++)
#pragma unroll
        for (int j = 0; j < 2; j++) acc[i][j] = (f32x4){0.f, 0.f, 0.f, 0.f};

    const short8 zf = {0, 0, 0, 0, 0, 0, 0, 0};
#pragma unroll
    for (int kc = 0; kc < 2; kc++) {
        int cio = kc * 32 + q * 8;
#pragma unroll
        for (int dy = 0; dy < 3; dy++) {
            int gy = y + dy - 1;
            bool rok = (unsigned)gy < 64u;
            int gyc = min(max(gy, 0), 63);
#pragma unroll
            for (int dx = 0; dx < 3; dx++) {
                int tap = dy * 3 + dx;
                short8 Bf[2][3];
#pragma unroll
                for (int nt = 0; nt < 2; nt++)
#pragma unroll
                    for (int tm = 0; tm < 3; tm++)
                        Bf[nt][tm] = *(const short8*)(W1s +
                            (((size_t)tm * 9 + tap) * 128 + cobase + nt * 16 + n) * 64 + cio);
#pragma unroll
                for (int xt = 0; xt < 4; xt++) {
                    int gx = xt * 16 + n + dx - 1;
                    bool ok = rok && ((unsigned)gx < 64u);
                    int gxc = min(max(gx, 0), 63);
                    short8 Af = *(const short8*)(s0p + ((size_t)(gyc * 64 + gxc)) * 64 + cio);
                    Af = ok ? Af : zf;
#pragma unroll
                    for (int nt = 0; nt < 2; nt++)
#pragma unroll
                        for (int tm = 0; tm < 3; tm++)
                            acc[xt][nt] = __builtin_amdgcn_mfma_f32_16x16x32_bf16(
                                Af, Bf[nt][tm], acc[xt][nt], 0, 0, 0);
                }
            }
        }
    }

    size_t base_b = (size_t)b * 64 * 64 * 128;
#pragma unroll
    for (int xt = 0; xt < 4; xt++)
#pragma unroll
        for (int nt = 0; nt < 2; nt++) {
            int co = cobase + nt * 16 + n;
            int x0 = xt * 16 + q * 4;
#pragma unroll
            for (int r = 0; r < 4; r++) {
                size_t pos = base_b + ((size_t)(y * 64 + x0 + r)) * 128 + co;
                float2 mv = *(float2*)&mvs1[pos * 2];
                float pprev = sp1b[pos] ? 1.f : 0.f;
                float m = mv.x, s = mv.y, spk;
                srm(m, s, pprev, acc[xt][nt][r], spk);
                *(float2*)&mvs1[pos * 2] = make_float2(m, s);
                sp1b[pos] = spk > 0.5f ? SPK1 : 0;
            }
        }
}

// ============ pool1: sp1b [b][64][64][128] -> p1b [b][32][32][128] (bf16) ============
__global__ __launch_bounds__(256) void k_pool1(const unsigned short* __restrict__ sp1b,
                                               unsigned short* __restrict__ p1b) {
    int idx = blockIdx.x * 256 + threadIdx.x;   // 16*32*32*16 = 262144
    int c8 = idx & 15, x = (idx >> 4) & 31, y = (idx >> 9) & 31, b = idx >> 14;
    int c0 = c8 * 8;
    const unsigned short* sb = sp1b + (size_t)b * 64 * 64 * 128;
    const unsigned short* a0 = sb + ((size_t)(2 * y) * 64 + 2 * x) * 128 + c0;
    const unsigned short* a1 = a0 + 128;
    const unsigned short* a2 = a0 + 64 * 128;
    const unsigned short* a3 = a2 + 128;
    unsigned short o[8];
#pragma unroll
    for (int j = 0; j < 8; j++) {
        unsigned short v = a0[j];
        v = max(v, a1[j]); v = max(v, a2[j]); v = max(v, a3[j]);
        o[j] = v;
    }
    unsigned short* dst = p1b + ((size_t)b * 32 * 32 + y * 32 + x) * 128 + c0;
#pragma unroll
    for (int j = 0; j < 8; j++) dst[j] = o[j];
}

// ============ conv2 MFMA: p1b[b][32][32][128] -> SRM(NHWC) + sp2b ============
// grid: 16b*32y = 512 blocks, 256 thr. Wave: co-tile 32, x 0..31 (2 xt), kc 0..3.
__global__ __launch_bounds__(256) void k_conv2(const unsigned short* __restrict__ p1b,
                                               const unsigned short* __restrict__ W2s,
                                               float* __restrict__ mvs2,
                                               unsigned short* __restrict__ sp2b) {
    int y = blockIdx.x & 31, b = blockIdx.x >> 5;
    int lane = threadIdx.x & 63, wv = threadIdx.x >> 6;
    int n = lane & 15, q = lane >> 4;
    int cobase = wv * 32;
    const unsigned short* sbp = p1b + (size_t)b * 32 * 32 * 128;

    f32x4 acc[2][2];
#pragma unroll
    for (int i = 0; i < 2; i++)
#pragma unroll
        for (int j = 0; j < 2; j++) acc[i][j] = (f32x4){0.f, 0.f, 0.f, 0.f};

    const short8 zf = {0, 0, 0, 0, 0, 0, 0, 0};
    for (int kc = 0; kc < 4; kc++) {
        int cio = kc * 32 + q * 8;
#pragma unroll
        for (int dy = 0; dy < 3; dy++) {
            int gy = y + dy - 1;
            bool rok = (unsigned)gy < 32u;
            int gyc = min(max(gy, 0), 31);
#pragma unroll
            for (int dx = 0; dx < 3; dx++) {
                int tap = dy * 3 + dx;
                short8 Bf[2][3];
#pragma unroll
                for (int nt = 0; nt < 2; nt++)
#pragma unroll
                    for (int tm = 0; tm < 3; tm++)
                        Bf[nt][tm] = *(const short8*)(W2s +
                            (((size_t)tm * 9 + tap) * 128 + cobase + nt * 16 + n) * 128 + cio);
#pragma unroll
                for (int xt = 0; xt < 2; xt++) {
                    int gx = xt * 16 + n + dx - 1;
                    bool ok = rok && ((unsigned)gx < 32u);
                    int gxc = min(max(gx, 0), 31);
                    short8 Af = *(const short8*)(sbp + ((size_t)(gyc * 32 + gxc)) * 128 + cio);
                    Af = ok ? Af : zf;
#pragma unroll
                    for (int nt = 0; nt < 2; nt++)
#pragma unroll
                        for (int tm = 0; tm < 3; tm++)
                            acc[xt][nt] = __builtin_amdgcn_mfma_f32_16x16x32_bf16(
                                Af, Bf[nt][tm], acc[xt][nt], 0, 0, 0);
                }
            }
        }
    }

    size_t base_b = (size_t)b * 32 * 32 * 128;
#pragma unroll
    for (int xt = 0; xt < 2; xt++)
#pragma unroll
        for (int nt = 0; nt < 2; nt++) {
            int co = cobase + nt * 16 + n;
            int x0 = xt * 16 + q * 4;
#pragma unroll
            for (int r = 0; r < 4; r++) {
                size_t pos = base_b + ((size_t)(y * 32 + x0 + r)) * 128 + co;
                float2 mv = *(float2*)&mvs2[pos * 2];
                float pprev = sp2b[pos] ? 1.f : 0.f;
                float m = mv.x, s = mv.y, spk;
                srm(m, s, pprev, acc[xt][nt][r], spk);
                *(float2*)&mvs2[pos * 2] = make_float2(m, s);
                sp2b[pos] = spk > 0.5f ? SPK1 : 0;
            }
        }
}

// ============ pool2: sp2b [b][32][32][128] -> p2 fp32 NCHW flat [b][32768] ============
__global__ __launch_bounds__(256) void k_pool2(const unsigned short* __restrict__ sp2b,
                                               float* __restrict__ p2) {
    int idx = blockIdx.x * 256 + threadIdx.x;   // 16*16*16*16 = 65536
    int c8 = idx & 15, x = (idx >> 4) & 15, y = (idx >> 8) & 15, b = idx >> 12;
    int c0 = c8 * 8;
    const unsigned short* sb = sp2b + (size_t)b * 32 * 32 * 128;
    const unsigned short* a0 = sb + ((size_t)(2 * y) * 32 + 2 * x) * 128 + c0;
    const unsigned short* a1 = a0 + 128;
    const unsigned short* a2 = a0 + 32 * 128;
    const unsigned short* a3 = a2 + 128;
    float* dst = p2 + (size_t)b * 32768 + y * 16 + x;
#pragma unroll
    for (int j = 0; j < 8; j++) {
        unsigned short v = a0[j];
        v = max(v, a1[j]); v = max(v, a2[j]); v = max(v, a3[j]);
        dst[(size_t)(c0 + j) * 256] = v ? 1.f : 0.f;
    }
}

// ============ fc3 partial: p2[16,32768] @ W3^T -> I3p[KS3][16][512] ============
// grid 512 = 32 ot x 16 ks; block 256 (4 waves). Wave: 4 o x 16 b over k-slice 2048.
// Lanes run along k (coalesced W3 stream); butterfly-reduce across lanes at end.
__global__ __launch_bounds__(256) void k_fc3(const float* __restrict__ p2,
                                             const float* __restrict__ W3,
                                             float* __restrict__ I3p) {
    int ot = blockIdx.x & 31, ks = blockIdx.x >> 5;
    int lane = threadIdx.x & 63, wv = threadIdx.x >> 6;
    int o0 = ot * 16 + wv * 4;
    float acc[4][16];
#pragma unroll
    for (int o = 0; o < 4; o++)
#pragma unroll
        for (int b = 0; b < 16; b++) acc[o][b] = 0.f;

    int kb = ks * 2048 + lane * 4;
#pragma unroll
    for (int kk = 0; kk < 8; kk++) {
        int k = kb + kk * 256;
        float4 w4[4];
#pragma unroll
        for (int o = 0; o < 4; o++)
            w4[o] = *(const float4*)(W3 + (size_t)(o0 + o) * 32768 + k);
#pragma unroll
        for (int b = 0; b < 16; b++) {
            float4 pv = *(const float4*)(p2 + (size_t)b * 32768 + k);
#pragma unroll
            for (int o = 0; o < 4; o++)
                acc[o][b] += w4[o].x * pv.x + w4[o].y * pv.y +
                             w4[o].z * pv.z + w4[o].w * pv.w;
        }
    }
    // butterfly: every lane ends with every (o,b) total
#pragma unroll
    for (int o = 0; o < 4; o++)
#pragma unroll
        for (int b = 0; b < 16; b++)
#pragma unroll
            for (int d = 1; d < 64; d <<= 1)
                acc[o][b] += __shfl_xor(acc[o][b], d);

    int b = lane & 15, osl = lane >> 4;
    float v = 0.f;
#pragma unroll
    for (int o = 0; o < 4; o++)
#pragma unroll
        for (int bb = 0; bb < 16; bb++)
            if (osl == o && b == bb) v = acc[o][bb];
    I3p[(size_t)ks * 8192 + b * 512 + o0 + osl] = v;
}

// ============ srm3: reduce KS3 partials + SRM -> sp3 [16,512] ============
__global__ __launch_bounds__(256) void k_srm3(const float* __restrict__ I3p,
                                              float* __restrict__ vm, float* __restrict__ vs,
                                              float* __restrict__ sp) {
    int idx = blockIdx.x * 256 + threadIdx.x;
    float I = 0.f;
#pragma unroll
    for (int s = 0; s < KS3; s++) I += I3p[s * 8192 + idx];
    float m = vm[idx], s_ = vs[idx], p = sp[idx], spk;
    srm(m, s_, p, I, spk);
    vm[idx] = m; vs[idx] = s_; sp[idx] = spk;
}

// ============ fc4 + srm4 + accumulate ============
__global__ __launch_bounds__(256) void k_fc4(const float* __restrict__ sp3,
                                             const float* __restrict__ W4,
                                             float* __restrict__ vm, float* __restrict__ vs,
                                             float* __restrict__ sp, float* __restrict__ out) {
    int tid = threadIdx.x;
    if (tid >= N4) return;
    int b = tid / 11, o = tid - b * 11;
    const float4* a = (const float4*)(sp3 + b * 512);
    const float4* w = (const float4*)(W4 + o * 512);
    float acc = 0.f;
    for (int k = 0; k < 128; k++) {
        float4 x = a[k], y = w[k];
        acc += x.x * y.x + x.y * y.y + x.z * y.z + x.w * y.w;
    }
    float m = vm[tid], s = vs[tid], p = sp[tid], spk;
    srm(m, s, p, acc, spk);
    vm[tid] = m; vs[tid] = s; sp[tid] = spk;
    out[tid] += spk * 0.0625f;
}

extern "C" void kernel_launch(void* const* d_in, const int* in_sizes, int n_in,
                              void* d_out, int out_size, void* d_ws, size_t ws_size,
                              hipStream_t stream) {
    const float* in = (const float*)d_in[0];
    const float* W0 = (const float*)d_in[1];
    const float* W1 = (const float*)d_in[2];
    const float* W2 = (const float*)d_in[3];
    const float* W3 = (const float*)d_in[4];
    const float* W4 = (const float*)d_in[5];
    float* out = (float*)d_out;
    char* ws = (char*)d_ws;

    size_t off = 0;
    auto allocf = [&](size_t n) { float* p = (float*)(ws + off); off += n * 4; return p; };
    auto allocu = [&](size_t n) { unsigned short* p = (unsigned short*)(ws + off); off += n * 2; return p; };

    // ---- zero-init region (SRM state + persistent spike tensors) ----
    float* mvs0 = allocf((size_t)N0 * 2);
    float* mvs1 = allocf((size_t)N1 * 2);
    float* mvs2 = allocf((size_t)N2 * 2);
    float* vm3 = allocf(N3); float* vs3 = allocf(N3); float* sp3 = allocf(N3);
    float* vm4 = allocf(N4); float* vs4 = allocf(N4); float* sp4 = allocf(N4);
    unsigned short* s0b = allocu(N0);
    unsigned short* sp1b = allocu(N1);
    unsigned short* sp2b = allocu(N2);
    size_t zbytes = off;

    // ---- scratch (fully rewritten each step) ----
    unsigned short* p1b = allocu(N2);
    float* p2 = allocf(P2N);
    float* I3p = allocf(I3PN);
    unsigned short* W1s = allocu((size_t)3 * 9 * 128 * 64);
    unsigned short* W2s = allocu((size_t)3 * 9 * 128 * 128);

    hipMemsetAsync(d_ws, 0, zbytes, stream);
    hipMemsetAsync(d_out, 0, N4 * sizeof(float), stream);

    k_prep<<<(9 * 128 * 64 + 255) / 256, 256, 0, stream>>>(W1, W1s, 128, 64);
    k_prep<<<(9 * 128 * 128 + 255) / 256, 256, 0, stream>>>(W2, W2s, 128, 128);

    for (int t = 0; t < T; t++) {
        k_conv0<<<B * 8 * 8, 128, 0, stream>>>(in, W0, mvs0, s0b, t);
        k_conv1<<<B * 64, 256, 0, stream>>>(s0b, W1s, mvs1, sp1b);
        k_pool1<<<262144 / 256, 256, 0, stream>>>(sp1b, p1b);
        k_conv2<<<B * 32, 256, 0, stream>>>(p1b, W2s, mvs2, sp2b);
        k_pool2<<<65536 / 256, 256, 0, stream>>>(sp2b, p2);
        k_fc3<<<32 * KS3, 256, 0, stream>>>(p2, W3, I3p);
        k_srm3<<<N3 / 256, 256, 0, stream>>>(I3p, vm3, vs3, sp3);
        k_fc4<<<1, 256, 0, stream>>>(sp3, W4, vm4, vs4, sp4, out);
    }
}

// Round 6
// 4199.866 us; speedup vs baseline: 4.1719x; 1.0604x over previous
//
#include <hip/hip_runtime.h>
#include <hip/hip_bf16.h>

// SRM constants (match reference: float(np.exp(-1/16)), float(np.exp(-1/4)))
#define DM 0.9394130628134758f
#define DSC 0.7788007830714049f
#define TH 0.3f

#define B 16
#define T 16

typedef short short8 __attribute__((ext_vector_type(8)));
typedef float f32x4 __attribute__((ext_vector_type(4)));

#define SPK1 ((unsigned short)0x3F80)  // bf16 1.0

__device__ __forceinline__ void srm(float& m, float& s, float p, float I, float& spk) {
    m = DM * m * (1.f - p) + I;
    s = DSC * s * (1.f - p) + I;
    spk = (m - s > TH) ? 1.f : 0.f;
}

// ============ weight prep: fp32 OIHW -> 3-term bf16 [term][tap][co][ci] ============
__global__ __launch_bounds__(256) void k_prep(const float* __restrict__ W,
                                              unsigned short* __restrict__ Ws,
                                              int CO, int CI) {
    int idx = blockIdx.x * 256 + threadIdx.x;
    int total = CO * CI * 9;
    if (idx >= total) return;
    int tap = idx % 9, tmp = idx / 9, ci = tmp % CI, co = tmp / CI;
    float w = W[((size_t)co * CI + ci) * 9 + tap];
    __hip_bfloat16 h = __float2bfloat16(w);
    float hf = __bfloat162float(h);
    __hip_bfloat16 mdd = __float2bfloat16(w - hf);
    float mf = __bfloat162float(mdd);
    __hip_bfloat16 lo = __float2bfloat16(w - hf - mf);
    size_t base = ((size_t)tap * CO + co) * CI + ci;
    size_t stride = (size_t)9 * CO * CI;
    Ws[base] = *(unsigned short*)&h;
    Ws[base + stride] = *(unsigned short*)&mdd;
    Ws[base + 2 * stride] = *(unsigned short*)&lo;
}

// ============ conv0T: all 16 steps, state in regs -> s0b_all [t][b][y][x][64ci] bf16 ====
// grid: 16b*8yt*8cog = 1024 blocks, 128 thr. Thread: 8 rows? no: ty row, 4 x, 8 co.
#define S0 68
__global__ __launch_bounds__(128) void k_conv0T(const float* __restrict__ in,
                                                const float* __restrict__ W0,
                                                unsigned short* __restrict__ s0b) {
    __shared__ float tile[2][10 * S0];
    int bid = blockIdx.x;
    int cog = bid & 7, yt = (bid >> 3) & 7, b = bid >> 6;
    int tid = threadIdx.x;
    int tx = (tid & 15) * 4, ty = tid >> 4;   // ty 0..7
    int y0 = yt * 8, y = y0 + ty;

    float m[8][4] = {}, s[8][4] = {};
    unsigned pmask = 0;                        // bit c*4+j

    for (int t = 0; t < T; t++) {
        if (t) __syncthreads();
        for (int i = tid; i < 2 * 660; i += 128) {
            int cl = i / 660, rem = i - cl * 660;
            int r = rem / 66, c = rem - r * 66;
            int gy = y0 + r - 1, gx = c - 1;
            float v = 0.f;
            if ((unsigned)gy < 64u && (unsigned)gx < 64u) {
                const float* src = in + ((size_t)((b * T + t) * 2 + cl)) * 4096;
                v = fminf(fmaxf(src[gy * 64 + gx], 0.f), 1.f);
            }
            tile[cl][r * S0 + c] = v;
        }
        __syncthreads();

        float acc[8][4] = {};
#pragma unroll
        for (int cl = 0; cl < 2; cl++) {
            const float* wb = W0 + ((size_t)cog * 8 * 2 + cl) * 9;
#pragma unroll
            for (int dy = 0; dy < 3; dy++) {
                float4 A = *(const float4*)&tile[cl][(ty + dy) * S0 + tx];
                float4 Bv = *(const float4*)&tile[cl][(ty + dy) * S0 + tx + 4];
                float r0 = A.x, r1 = A.y, r2 = A.z, r3 = A.w, r4 = Bv.x, r5 = Bv.y;
#pragma unroll
                for (int c = 0; c < 8; c++) {
                    const float* w = wb + (size_t)c * 2 * 9 + dy * 3;
                    float wa = w[0], wbx = w[1], wc = w[2];
                    acc[c][0] += wa * r0 + wbx * r1 + wc * r2;
                    acc[c][1] += wa * r1 + wbx * r2 + wc * r3;
                    acc[c][2] += wa * r2 + wbx * r3 + wc * r4;
                    acc[c][3] += wa * r3 + wbx * r4 + wc * r5;
                }
            }
        }

        unsigned newmask = 0;
        unsigned short* s0p = s0b + ((size_t)(t * 16 + b) * 4096) * 64;
#pragma unroll
        for (int j = 0; j < 4; j++) {
            short8 sv;
#pragma unroll
            for (int c = 0; c < 8; c++) {
                int bit = c * 4 + j;
                float p = (pmask >> bit) & 1 ? 1.f : 0.f;
                float spk;
                srm(m[c][j], s[c][j], p, acc[c][j], spk);
                bool on = spk > 0.5f;
                if (on) newmask |= 1u << bit;
                sv[c] = on ? (short)SPK1 : (short)0;
            }
            *(short8*)(s0p + ((size_t)(y * 64 + tx + j)) * 64 + cog * 8) = sv;
        }
        pmask = newmask;
    }
}

// ============ conv1T MFMA: all 16 steps, state in regs, fused pool ============
// grid: 16b*32yp*2cog = 1024 blocks, 256 thr (4 waves).
// Wave: 2 y rows (y0,y0+1) x 64 x x 16 co. Writes p1b_all [t][b][32][32][128] bf16.
__global__ __launch_bounds__(256) void k_conv1T(const unsigned short* __restrict__ s0b,
                                                const unsigned short* __restrict__ W1s,
                                                unsigned short* __restrict__ p1b) {
    int bid = blockIdx.x;
    int cog = bid & 1, yp = (bid >> 1) & 31, b = bid >> 6;
    int lane = threadIdx.x & 63, wv = threadIdx.x >> 6;
    int n = lane & 15, q = lane >> 4;
    int cobase = cog * 64 + wv * 16;
    int y0 = yp * 2;

    float sm[2][4][4] = {}, ss[2][4][4] = {};   // [yo][xt][r]
    unsigned pmask = 0;                          // bit yo*16 + xt*4 + r
    const short8 zf = {0, 0, 0, 0, 0, 0, 0, 0};

    for (int t = 0; t < T; t++) {
        f32x4 acc[2][4];
#pragma unroll
        for (int i = 0; i < 2; i++)
#pragma unroll
            for (int j = 0; j < 4; j++) acc[i][j] = (f32x4){0.f, 0.f, 0.f, 0.f};

        const unsigned short* sb = s0b + ((size_t)(t * 16 + b) * 4096) * 64;
#pragma unroll
        for (int kc = 0; kc < 2; kc++) {
            int cio = kc * 32 + q * 8;
#pragma unroll
            for (int r = 0; r < 4; r++) {
                int gy = y0 - 1 + r;
                if (gy < 0 || gy > 63) continue;        // wave-uniform
#pragma unroll
                for (int dx = 0; dx < 3; dx++) {
                    short8 Af[4];
#pragma unroll
                    for (int xt = 0; xt < 4; xt++) {
                        int gx = xt * 16 + n + dx - 1;
                        bool ok = (unsigned)gx < 64u;
                        int gxc = min(max(gx, 0), 63);
                        short8 a = *(const short8*)(sb + ((size_t)(gy * 64 + gxc)) * 64 + cio);
                        Af[xt] = ok ? a : zf;
                    }
#pragma unroll
                    for (int yo = 0; yo < 2; yo++) {
                        int dy = r - yo;
                        if (dy < 0 || dy > 2) continue; // compile-time after unroll
                        int tap = dy * 3 + dx;
#pragma unroll
                        for (int tm = 0; tm < 3; tm++) {
                            short8 Bf = *(const short8*)(W1s +
                                (((size_t)tm * 9 + tap) * 128 + cobase + n) * 64 + kc * 32 + q * 8);
#pragma unroll
                            for (int xt = 0; xt < 4; xt++)
                                acc[yo][xt] = __builtin_amdgcn_mfma_f32_16x16x32_bf16(
                                    Af[xt], Bf, acc[yo][xt], 0, 0, 0);
                        }
                    }
                }
            }
        }

        // SRM (state in regs) + fused 2x2 pool (bit-OR) + store
        unsigned newmask = 0;
#pragma unroll
        for (int yo = 0; yo < 2; yo++)
#pragma unroll
            for (int xt = 0; xt < 4; xt++)
#pragma unroll
                for (int r = 0; r < 4; r++) {
                    int bit = yo * 16 + xt * 4 + r;
                    float p = (pmask >> bit) & 1 ? 1.f : 0.f;
                    float spk;
                    srm(sm[yo][xt][r], ss[yo][xt][r], p, acc[yo][xt][r], spk);
                    if (spk > 0.5f) newmask |= 1u << bit;
                }
        pmask = newmask;

        unsigned short* pb = p1b + (((size_t)(t * 16 + b) * 1024) + yp * 32) * 128 + cobase + n;
#pragma unroll
        for (int xt = 0; xt < 4; xt++)
#pragma unroll
            for (int rp = 0; rp < 2; rp++) {
                int i00 = xt * 4 + 2 * rp;
                unsigned on = ((newmask >> i00) | (newmask >> (i00 + 1)) |
                               (newmask >> (i00 + 16)) | (newmask >> (i00 + 17))) & 1u;
                int xp = xt * 8 + q * 2 + rp;
                pb[(size_t)xp * 128] = on ? SPK1 : (unsigned short)0;
            }
    }
}

// ============ conv2T MFMA: all 16 steps, state in regs, fused pool ============
// grid: 16b*16yp*2cog = 512 blocks, 256 thr. Wave: 2y x 32x x 16co.
// Writes p2_all fp32 NCHW [t][b][128c][16y][16x].
__global__ __launch_bounds__(256) void k_conv2T(const unsigned short* __restrict__ p1b,
                                                const unsigned short* __restrict__ W2s,
                                                float* __restrict__ p2) {
    int bid = blockIdx.x;
    int cog = bid & 1, yp = (bid >> 1) & 15, b = bid >> 5;
    int lane = threadIdx.x & 63, wv = threadIdx.x >> 6;
    int n = lane & 15, q = lane >> 4;
    int cobase = cog * 64 + wv * 16;
    int y0 = yp * 2;

    float sm[2][2][4] = {}, ss[2][2][4] = {};   // [yo][xt][r]
    unsigned pmask = 0;                          // bit yo*8 + xt*4 + r
    const short8 zf = {0, 0, 0, 0, 0, 0, 0, 0};

    for (int t = 0; t < T; t++) {
        f32x4 acc[2][2];
#pragma unroll
        for (int i = 0; i < 2; i++)
#pragma unroll
            for (int j = 0; j < 2; j++) acc[i][j] = (f32x4){0.f, 0.f, 0.f, 0.f};

        const unsigned short* sb = p1b + ((size_t)(t * 16 + b) * 1024) * 128;
#pragma unroll
        for (int kc = 0; kc < 4; kc++) {
            int cio = kc * 32 + q * 8;
#pragma unroll
            for (int r = 0; r < 4; r++) {
                int gy = y0 - 1 + r;
                if (gy < 0 || gy > 31) continue;
#pragma unroll
                for (int dx = 0; dx < 3; dx++) {
                    short8 Af[2];
#pragma unroll
                    for (int xt = 0; xt < 2; xt++) {
                        int gx = xt * 16 + n + dx - 1;
                        bool ok = (unsigned)gx < 32u;
                        int gxc = min(max(gx, 0), 31);
                        short8 a = *(const short8*)(sb + ((size_t)(gy * 32 + gxc)) * 128 + cio);
                        Af[xt] = ok ? a : zf;
                    }
#pragma unroll
                    for (int yo = 0; yo < 2; yo++) {
                        int dy = r - yo;
                        if (dy < 0 || dy > 2) continue;
                        int tap = dy * 3 + dx;
#pragma unroll
                        for (int tm = 0; tm < 3; tm++) {
                            short8 Bf = *(const short8*)(W2s +
                                (((size_t)tm * 9 + tap) * 128 + cobase + n) * 128 + kc * 32 + q * 8);
#pragma unroll
                            for (int xt = 0; xt < 2; xt++)
                                acc[yo][xt] = __builtin_amdgcn_mfma_f32_16x16x32_bf16(
                                    Af[xt], Bf, acc[yo][xt], 0, 0, 0);
                        }
                    }
                }
            }
        }

        unsigned newmask = 0;
#pragma unroll
        for (int yo = 0; yo < 2; yo++)
#pragma unroll
            for (int xt = 0; xt < 2; xt++)
#pragma unroll
                for (int r = 0; r < 4; r++) {
                    int bit = yo * 8 + xt * 4 + r;
                    float p = (pmask >> bit) & 1 ? 1.f : 0.f;
                    float spk;
                    srm(sm[yo][xt][r], ss[yo][xt][r], p, acc[yo][xt][r], spk);
                    if (spk > 0.5f) newmask |= 1u << bit;
                }
        pmask = newmask;

        float* pp = p2 + (size_t)(t * 16 + b) * 32768 + (size_t)(cobase + n) * 256 + yp * 16;
#pragma unroll
        for (int xt = 0; xt < 2; xt++)
#pragma unroll
            for (int rp = 0; rp < 2; rp++) {
                int i00 = xt * 4 + 2 * rp;
                unsigned on = ((newmask >> i00) | (newmask >> (i00 + 1)) |
                               (newmask >> (i00 + 8)) | (newmask >> (i00 + 9))) & 1u;
                int xp = xt * 8 + q * 2 + rp;
                pp[xp] = on ? 1.f : 0.f;
            }
    }
}

// ============ fc3T: all t, R5-identical inner math. p2[256][32768] @ W3^T -> I3p[t][16ks][8192]
// grid 512 = 32 ot x 16 ks; block 256 (4 waves). Wave: 4 o x 16 b per t, lanes along k.
__global__ __launch_bounds__(256) void k_fc3T(const float* __restrict__ p2,
                                              const float* __restrict__ W3,
                                              float* __restrict__ I3p) {
    int ot = blockIdx.x & 31, ks = blockIdx.x >> 5;
    int lane = threadIdx.x & 63, wv = threadIdx.x >> 6;
    int o0 = ot * 16 + wv * 4;
    int kb = ks * 2048 + lane * 4;

    for (int t = 0; t < T; t++) {
        float acc[4][16];
#pragma unroll
        for (int o = 0; o < 4; o++)
#pragma unroll
            for (int bb = 0; bb < 16; bb++) acc[o][bb] = 0.f;

#pragma unroll
        for (int kk = 0; kk < 8; kk++) {
            int k = kb + kk * 256;
            float4 w4[4];
#pragma unroll
            for (int o = 0; o < 4; o++)
                w4[o] = *(const float4*)(W3 + (size_t)(o0 + o) * 32768 + k);
#pragma unroll
            for (int bb = 0; bb < 16; bb++) {
                float4 pv = *(const float4*)(p2 + (size_t)(t * 16 + bb) * 32768 + k);
#pragma unroll
                for (int o = 0; o < 4; o++)
                    acc[o][bb] += w4[o].x * pv.x + w4[o].y * pv.y +
                                  w4[o].z * pv.z + w4[o].w * pv.w;
            }
        }
#pragma unroll
        for (int o = 0; o < 4; o++)
#pragma unroll
            for (int bb = 0; bb < 16; bb++)
#pragma unroll
                for (int d = 1; d < 64; d <<= 1)
                    acc[o][bb] += __shfl_xor(acc[o][bb], d);

        int bb = lane & 15, osl = lane >> 4;
        float v = 0.f;
#pragma unroll
        for (int o = 0; o < 4; o++)
#pragma unroll
            for (int b2 = 0; b2 < 16; b2++)
                if (osl == o && bb == b2) v = acc[o][b2];
        I3p[((size_t)(t * 16 + ks)) * 8192 + bb * 512 + o0 + osl] = v;
    }
}

// ============ srm3T: per neuron, scan t: reduce 16 partials + SRM -> sp3_all [t][8192]
__global__ __launch_bounds__(256) void k_srm3T(const float* __restrict__ I3p,
                                               float* __restrict__ sp3) {
    int idx = blockIdx.x * 256 + threadIdx.x;    // 8192
    float m = 0.f, s = 0.f, p = 0.f;
    for (int t = 0; t < T; t++) {
        float I = 0.f;
#pragma unroll
        for (int ks = 0; ks < 16; ks++) I += I3p[((size_t)(t * 16 + ks)) * 8192 + idx];
        float spk;
        srm(m, s, p, I, spk);
        p = spk;
        sp3[t * 8192 + idx] = spk;
    }
}

// ============ fc4g: I4[t*16+b][11] = sp3[t][b] @ W4^T ============
__global__ __launch_bounds__(256) void k_fc4g(const float* __restrict__ sp3,
                                              const float* __restrict__ W4,
                                              float* __restrict__ I4) {
    int t = blockIdx.x, tid = threadIdx.x;
    if (tid >= 176) return;
    int b = tid / 11, o = tid - b * 11;
    const float4* a = (const float4*)(sp3 + (size_t)t * 8192 + b * 512);
    const float4* w = (const float4*)(W4 + o * 512);
    float acc = 0.f;
    for (int k = 0; k < 128; k++) {
        float4 x = a[k], y = w[k];
        acc += x.x * y.x + x.y * y.y + x.z * y.z + x.w * y.w;
    }
    I4[(size_t)(t * 16 + b) * 11 + o] = acc;
}

// ============ fc4s: scan t with SRM, write out ============
__global__ __launch_bounds__(256) void k_fc4s(const float* __restrict__ I4,
                                              float* __restrict__ out) {
    int tid = threadIdx.x;
    if (tid >= 176) return;
    int b = tid / 11, o = tid - b * 11;
    float m = 0.f, s = 0.f, p = 0.f, sum = 0.f;
    for (int t = 0; t < T; t++) {
        float I = I4[(size_t)(t * 16 + b) * 11 + o];
        float spk;
        srm(m, s, p, I, spk);
        p = spk;
        sum += spk;
    }
    out[tid] = sum * 0.0625f;   // exact: integer count / 16
}

extern "C" void kernel_launch(void* const* d_in, const int* in_sizes, int n_in,
                              void* d_out, int out_size, void* d_ws, size_t ws_size,
                              hipStream_t stream) {
    const float* in = (const float*)d_in[0];
    const float* W0 = (const float*)d_in[1];
    const float* W1 = (const float*)d_in[2];
    const float* W2 = (const float*)d_in[3];
    const float* W3 = (const float*)d_in[4];
    const float* W4 = (const float*)d_in[5];
    float* out = (float*)d_out;
    char* ws = (char*)d_ws;

    size_t off = 0;
    auto alloc = [&](size_t bytes) {
        void* p = ws + off;
        off += (bytes + 255) & ~(size_t)255;
        return p;
    };
    // all buffers fully written before read each launch -> no memsets needed
    unsigned short* s0b = (unsigned short*)alloc((size_t)256 * 4096 * 64 * 2);   // 134.2 MB
    unsigned short* p1b = (unsigned short*)alloc((size_t)256 * 1024 * 128 * 2);  // 67.1 MB
    float* p2  = (float*)alloc((size_t)256 * 32768 * 4);                          // 33.6 MB
    float* I3p = (float*)alloc((size_t)256 * 8192 * 4);                           // 8.4 MB
    float* sp3 = (float*)alloc((size_t)16 * 8192 * 4);
    float* I4  = (float*)alloc((size_t)256 * 11 * 4);
    unsigned short* W1s = (unsigned short*)alloc((size_t)3 * 9 * 128 * 64 * 2);
    unsigned short* W2s = (unsigned short*)alloc((size_t)3 * 9 * 128 * 128 * 2);

    k_prep<<<(9 * 128 * 64 + 255) / 256, 256, 0, stream>>>(W1, W1s, 128, 64);
    k_prep<<<(9 * 128 * 128 + 255) / 256, 256, 0, stream>>>(W2, W2s, 128, 128);

    k_conv0T<<<16 * 8 * 8, 128, 0, stream>>>(in, W0, s0b);
    k_conv1T<<<16 * 32 * 2, 256, 0, stream>>>(s0b, W1s, p1b);
    k_conv2T<<<16 * 16 * 2, 256, 0, stream>>>(p1b, W2s, p2);
    k_fc3T<<<32 * 16, 256, 0, stream>>>(p2, W3, I3p);
    k_srm3T<<<8192 / 256, 256, 0, stream>>>(I3p, sp3);
    k_fc4g<<<16, 256, 0, stream>>>(sp3, W4, I4);
    k_fc4s<<<1, 256, 0, stream>>>(I4, out);
}

// Round 7
// 3042.684 us; speedup vs baseline: 5.7586x; 1.3803x over previous
//
#include <hip/hip_runtime.h>
#include <hip/hip_bf16.h>

// SRM constants (match reference: float(np.exp(-1/16)), float(np.exp(-1/4)))
#define DM 0.9394130628134758f
#define DSC 0.7788007830714049f
#define TH 0.3f

#define B 16
#define T 16

typedef short short8 __attribute__((ext_vector_type(8)));
typedef float f32x4 __attribute__((ext_vector_type(4)));

#define SPK1 ((unsigned short)0x3F80)  // bf16 1.0

__device__ __forceinline__ void srm(float& m, float& s, float p, float I, float& spk) {
    m = DM * m * (1.f - p) + I;
    s = DSC * s * (1.f - p) + I;
    spk = (m - s > TH) ? 1.f : 0.f;
}

// ============ weight prep: fp32 OIHW -> 3-term bf16 [term][tap][co][ci] ============
__global__ __launch_bounds__(256) void k_prep(const float* __restrict__ W,
                                              unsigned short* __restrict__ Ws,
                                              int CO, int CI) {
    int idx = blockIdx.x * 256 + threadIdx.x;
    int total = CO * CI * 9;
    if (idx >= total) return;
    int tap = idx % 9, tmp = idx / 9, ci = tmp % CI, co = tmp / CI;
    float w = W[((size_t)co * CI + ci) * 9 + tap];
    __hip_bfloat16 h = __float2bfloat16(w);
    float hf = __bfloat162float(h);
    __hip_bfloat16 mdd = __float2bfloat16(w - hf);
    float mf = __bfloat162float(mdd);
    __hip_bfloat16 lo = __float2bfloat16(w - hf - mf);
    size_t base = ((size_t)tap * CO + co) * CI + ci;
    size_t stride = (size_t)9 * CO * CI;
    Ws[base] = *(unsigned short*)&h;
    Ws[base + stride] = *(unsigned short*)&mdd;
    Ws[base + 2 * stride] = *(unsigned short*)&lo;
}

// ============ conv0T: all 16 steps, state in regs -> s0b_all [t][b][y][x][64ci] bf16 ====
// grid: 16b*8yt*8cog = 1024 blocks, 128 thr.
#define S0 68
__global__ __launch_bounds__(128) void k_conv0T(const float* __restrict__ in,
                                                const float* __restrict__ W0,
                                                unsigned short* __restrict__ s0b) {
    __shared__ float tile[2][10 * S0];
    int bid = blockIdx.x;
    int cog = bid & 7, yt = (bid >> 3) & 7, b = bid >> 6;
    int tid = threadIdx.x;
    int tx = (tid & 15) * 4, ty = tid >> 4;   // ty 0..7
    int y0 = yt * 8, y = y0 + ty;

    float m[8][4] = {}, s[8][4] = {};
    unsigned pmask = 0;                        // bit c*4+j

    for (int t = 0; t < T; t++) {
        if (t) __syncthreads();
        for (int i = tid; i < 2 * 660; i += 128) {
            int cl = i / 660, rem = i - cl * 660;
            int r = rem / 66, c = rem - r * 66;
            int gy = y0 + r - 1, gx = c - 1;
            float v = 0.f;
            if ((unsigned)gy < 64u && (unsigned)gx < 64u) {
                const float* src = in + ((size_t)((b * T + t) * 2 + cl)) * 4096;
                v = fminf(fmaxf(src[gy * 64 + gx], 0.f), 1.f);
            }
            tile[cl][r * S0 + c] = v;
        }
        __syncthreads();

        float acc[8][4] = {};
#pragma unroll
        for (int cl = 0; cl < 2; cl++) {
            const float* wb = W0 + ((size_t)cog * 8 * 2 + cl) * 9;
#pragma unroll
            for (int dy = 0; dy < 3; dy++) {
                float4 A = *(const float4*)&tile[cl][(ty + dy) * S0 + tx];
                float4 Bv = *(const float4*)&tile[cl][(ty + dy) * S0 + tx + 4];
                float r0 = A.x, r1 = A.y, r2 = A.z, r3 = A.w, r4 = Bv.x, r5 = Bv.y;
#pragma unroll
                for (int c = 0; c < 8; c++) {
                    const float* w = wb + (size_t)c * 2 * 9 + dy * 3;
                    float wa = w[0], wbx = w[1], wc = w[2];
                    acc[c][0] += wa * r0 + wbx * r1 + wc * r2;
                    acc[c][1] += wa * r1 + wbx * r2 + wc * r3;
                    acc[c][2] += wa * r2 + wbx * r3 + wc * r4;
                    acc[c][3] += wa * r3 + wbx * r4 + wc * r5;
                }
            }
        }

        unsigned newmask = 0;
        unsigned short* s0p = s0b + ((size_t)(t * 16 + b) * 4096) * 64;
#pragma unroll
        for (int j = 0; j < 4; j++) {
            short8 sv;
#pragma unroll
            for (int c = 0; c < 8; c++) {
                int bit = c * 4 + j;
                float p = (pmask >> bit) & 1 ? 1.f : 0.f;
                float spk;
                srm(m[c][j], s[c][j], p, acc[c][j], spk);
                bool on = spk > 0.5f;
                if (on) newmask |= 1u << bit;
                sv[c] = on ? (short)SPK1 : (short)0;
            }
            *(short8*)(s0p + ((size_t)(y * 64 + tx + j)) * 64 + cog * 8) = sv;
        }
        pmask = newmask;
    }
}

// ============ conv1T MFMA: all 16 steps, state in regs, fused pool ============
// grid 1024, 256 thr (4 waves). XCD-pinned: blockIdx&7 == b&7 (L2 locality under t-drift).
// Wave: 2 y rows x 64 x x 16 co. Writes p1b_all [t][b][32][32][128] bf16.
__global__ __launch_bounds__(256) void k_conv1T(const unsigned short* __restrict__ s0b,
                                                const unsigned short* __restrict__ W1s,
                                                unsigned short* __restrict__ p1b) {
    int i = blockIdx.x;
    int xcd = i & 7, rest = i >> 3;            // rest in [0,128)
    int b = ((rest & 1) << 3) | xcd;
    int yp = (rest >> 1) & 31;
    int cog = (rest >> 6) & 1;
    int lane = threadIdx.x & 63, wv = threadIdx.x >> 6;
    int n = lane & 15, q = lane >> 4;
    int cobase = cog * 64 + wv * 16;
    int y0 = yp * 2;

    float sm[2][4][4] = {}, ss[2][4][4] = {};   // [yo][xt][r]
    unsigned pmask = 0;                          // bit yo*16 + xt*4 + r
    const short8 zf = {0, 0, 0, 0, 0, 0, 0, 0};

    for (int t = 0; t < T; t++) {
        f32x4 acc[2][4];
#pragma unroll
        for (int i2 = 0; i2 < 2; i2++)
#pragma unroll
            for (int j = 0; j < 4; j++) acc[i2][j] = (f32x4){0.f, 0.f, 0.f, 0.f};

        const unsigned short* sb = s0b + ((size_t)(t * 16 + b) * 4096) * 64;
#pragma unroll
        for (int kc = 0; kc < 2; kc++) {
            int cio = kc * 32 + q * 8;
#pragma unroll
            for (int r = 0; r < 4; r++) {
                int gy = y0 - 1 + r;
                if (gy < 0 || gy > 63) continue;        // wave-uniform
#pragma unroll
                for (int dx = 0; dx < 3; dx++) {
                    short8 Af[4];
#pragma unroll
                    for (int xt = 0; xt < 4; xt++) {
                        int gx = xt * 16 + n + dx - 1;
                        bool ok = (unsigned)gx < 64u;
                        int gxc = min(max(gx, 0), 63);
                        short8 a = *(const short8*)(sb + ((size_t)(gy * 64 + gxc)) * 64 + cio);
                        Af[xt] = ok ? a : zf;
                    }
#pragma unroll
                    for (int yo = 0; yo < 2; yo++) {
                        int dy = r - yo;
                        if (dy < 0 || dy > 2) continue; // compile-time after unroll
                        int tap = dy * 3 + dx;
#pragma unroll
                        for (int tm = 0; tm < 3; tm++) {
                            short8 Bf = *(const short8*)(W1s +
                                (((size_t)tm * 9 + tap) * 128 + cobase + n) * 64 + kc * 32 + q * 8);
#pragma unroll
                            for (int xt = 0; xt < 4; xt++)
                                acc[yo][xt] = __builtin_amdgcn_mfma_f32_16x16x32_bf16(
                                    Af[xt], Bf, acc[yo][xt], 0, 0, 0);
                        }
                    }
                }
            }
        }

        // SRM (state in regs) + fused 2x2 pool (bit-OR) + store
        unsigned newmask = 0;
#pragma unroll
        for (int yo = 0; yo < 2; yo++)
#pragma unroll
            for (int xt = 0; xt < 4; xt++)
#pragma unroll
                for (int r = 0; r < 4; r++) {
                    int bit = yo * 16 + xt * 4 + r;
                    float p = (pmask >> bit) & 1 ? 1.f : 0.f;
                    float spk;
                    srm(sm[yo][xt][r], ss[yo][xt][r], p, acc[yo][xt][r], spk);
                    if (spk > 0.5f) newmask |= 1u << bit;
                }
        pmask = newmask;

        unsigned short* pb = p1b + (((size_t)(t * 16 + b) * 1024) + yp * 32) * 128 + cobase + n;
#pragma unroll
        for (int xt = 0; xt < 4; xt++)
#pragma unroll
            for (int rp = 0; rp < 2; rp++) {
                int i00 = xt * 4 + 2 * rp;
                unsigned on = ((newmask >> i00) | (newmask >> (i00 + 1)) |
                               (newmask >> (i00 + 16)) | (newmask >> (i00 + 17))) & 1u;
                int xp = xt * 8 + q * 2 + rp;
                pb[(size_t)xp * 128] = on ? SPK1 : (unsigned short)0;
            }
    }
}

// ============ conv2T MFMA: all 16 steps, state in regs, fused pool ============
// grid 512, 256 thr. XCD-pinned: blockIdx&7 == b&7. Wave: 2y x 32x x 16co.
// Writes p2_all fp32 NCHW [t][b][128c][16y][16x].
__global__ __launch_bounds__(256) void k_conv2T(const unsigned short* __restrict__ p1b,
                                                const unsigned short* __restrict__ W2s,
                                                float* __restrict__ p2) {
    int i = blockIdx.x;
    int xcd = i & 7, rest = i >> 3;            // rest in [0,64)
    int b = ((rest & 1) << 3) | xcd;
    int yp = (rest >> 1) & 15;
    int cog = (rest >> 5) & 1;
    int lane = threadIdx.x & 63, wv = threadIdx.x >> 6;
    int n = lane & 15, q = lane >> 4;
    int cobase = cog * 64 + wv * 16;
    int y0 = yp * 2;

    float sm[2][2][4] = {}, ss[2][2][4] = {};   // [yo][xt][r]
    unsigned pmask = 0;                          // bit yo*8 + xt*4 + r
    const short8 zf = {0, 0, 0, 0, 0, 0, 0, 0};

    for (int t = 0; t < T; t++) {
        f32x4 acc[2][2];
#pragma unroll
        for (int i2 = 0; i2 < 2; i2++)
#pragma unroll
            for (int j = 0; j < 2; j++) acc[i2][j] = (f32x4){0.f, 0.f, 0.f, 0.f};

        const unsigned short* sb = p1b + ((size_t)(t * 16 + b) * 1024) * 128;
#pragma unroll
        for (int kc = 0; kc < 4; kc++) {
            int cio = kc * 32 + q * 8;
#pragma unroll
            for (int r = 0; r < 4; r++) {
                int gy = y0 - 1 + r;
                if (gy < 0 || gy > 31) continue;
#pragma unroll
                for (int dx = 0; dx < 3; dx++) {
                    short8 Af[2];
#pragma unroll
                    for (int xt = 0; xt < 2; xt++) {
                        int gx = xt * 16 + n + dx - 1;
                        bool ok = (unsigned)gx < 32u;
                        int gxc = min(max(gx, 0), 31);
                        short8 a = *(const short8*)(sb + ((size_t)(gy * 32 + gxc)) * 128 + cio);
                        Af[xt] = ok ? a : zf;
                    }
#pragma unroll
                    for (int yo = 0; yo < 2; yo++) {
                        int dy = r - yo;
                        if (dy < 0 || dy > 2) continue;
                        int tap = dy * 3 + dx;
#pragma unroll
                        for (int tm = 0; tm < 3; tm++) {
                            short8 Bf = *(const short8*)(W2s +
                                (((size_t)tm * 9 + tap) * 128 + cobase + n) * 128 + kc * 32 + q * 8);
#pragma unroll
                            for (int xt = 0; xt < 2; xt++)
                                acc[yo][xt] = __builtin_amdgcn_mfma_f32_16x16x32_bf16(
                                    Af[xt], Bf, acc[yo][xt], 0, 0, 0);
                        }
                    }
                }
            }
        }

        unsigned newmask = 0;
#pragma unroll
        for (int yo = 0; yo < 2; yo++)
#pragma unroll
            for (int xt = 0; xt < 2; xt++)
#pragma unroll
                for (int r = 0; r < 4; r++) {
                    int bit = yo * 8 + xt * 4 + r;
                    float p = (pmask >> bit) & 1 ? 1.f : 0.f;
                    float spk;
                    srm(sm[yo][xt][r], ss[yo][xt][r], p, acc[yo][xt][r], spk);
                    if (spk > 0.5f) newmask |= 1u << bit;
                }
        pmask = newmask;

        float* pp = p2 + (size_t)(t * 16 + b) * 32768 + (size_t)(cobase + n) * 256 + yp * 16;
#pragma unroll
        for (int xt = 0; xt < 2; xt++)
#pragma unroll
            for (int rp = 0; rp < 2; rp++) {
                int i00 = xt * 4 + 2 * rp;
                unsigned on = ((newmask >> i00) | (newmask >> (i00 + 1)) |
                               (newmask >> (i00 + 8)) | (newmask >> (i00 + 9))) & 1u;
                int xp = xt * 8 + q * 2 + rp;
                pp[xp] = on ? 1.f : 0.f;
            }
    }
}

// ============ fc3: per-t grid (t has no state). p2[t][16,32768] @ W3^T -> I3p[t][ks][8192]
// grid 8192 = 32 ot x 16 ks x 16 t; block 256 (4 waves). Wave: 4 o x 16 b, lanes along k.
__global__ __launch_bounds__(256) void k_fc3(const float* __restrict__ p2,
                                             const float* __restrict__ W3,
                                             float* __restrict__ I3p) {
    int ot = blockIdx.x & 31, ks = (blockIdx.x >> 5) & 15, t = blockIdx.x >> 9;
    int lane = threadIdx.x & 63, wv = threadIdx.x >> 6;
    int o0 = ot * 16 + wv * 4;
    int kb = ks * 2048 + lane * 4;

    float acc[4][16];
#pragma unroll
    for (int o = 0; o < 4; o++)
#pragma unroll
        for (int bb = 0; bb < 16; bb++) acc[o][bb] = 0.f;

#pragma unroll
    for (int kk = 0; kk < 8; kk++) {
        int k = kb + kk * 256;
        float4 w4[4];
#pragma unroll
        for (int o = 0; o < 4; o++)
            w4[o] = *(const float4*)(W3 + (size_t)(o0 + o) * 32768 + k);
#pragma unroll
        for (int bb = 0; bb < 16; bb++) {
            float4 pv = *(const float4*)(p2 + (size_t)(t * 16 + bb) * 32768 + k);
#pragma unroll
            for (int o = 0; o < 4; o++)
                acc[o][bb] += w4[o].x * pv.x + w4[o].y * pv.y +
                              w4[o].z * pv.z + w4[o].w * pv.w;
        }
    }
#pragma unroll
    for (int o = 0; o < 4; o++)
#pragma unroll
        for (int bb = 0; bb < 16; bb++)
#pragma unroll
            for (int d = 1; d < 64; d <<= 1)
                acc[o][bb] += __shfl_xor(acc[o][bb], d);

    int bb = lane & 15, osl = lane >> 4;
    float v = 0.f;
#pragma unroll
    for (int o = 0; o < 4; o++)
#pragma unroll
        for (int b2 = 0; b2 < 16; b2++)
            if (osl == o && bb == b2) v = acc[o][b2];
    I3p[((size_t)(t * 16 + ks)) * 8192 + bb * 512 + o0 + osl] = v;
}

// ============ srm3T: per neuron, scan t: reduce 16 partials + SRM -> sp3_all [t][8192]
__global__ __launch_bounds__(256) void k_srm3T(const float* __restrict__ I3p,
                                               float* __restrict__ sp3) {
    int idx = blockIdx.x * 256 + threadIdx.x;    // 8192
    float m = 0.f, s = 0.f, p = 0.f;
    for (int t = 0; t < T; t++) {
        float I = 0.f;
#pragma unroll
        for (int ks = 0; ks < 16; ks++) I += I3p[((size_t)(t * 16 + ks)) * 8192 + idx];
        float spk;
        srm(m, s, p, I, spk);
        p = spk;
        sp3[t * 8192 + idx] = spk;
    }
}

// ============ fc4g: I4[t*16+b][11] = sp3[t][b] @ W4^T ============
__global__ __launch_bounds__(256) void k_fc4g(const float* __restrict__ sp3,
                                              const float* __restrict__ W4,
                                              float* __restrict__ I4) {
    int t = blockIdx.x, tid = threadIdx.x;
    if (tid >= 176) return;
    int b = tid / 11, o = tid - b * 11;
    const float4* a = (const float4*)(sp3 + (size_t)t * 8192 + b * 512);
    const float4* w = (const float4*)(W4 + o * 512);
    float acc = 0.f;
    for (int k = 0; k < 128; k++) {
        float4 x = a[k], y = w[k];
        acc += x.x * y.x + x.y * y.y + x.z * y.z + x.w * y.w;
    }
    I4[(size_t)(t * 16 + b) * 11 + o] = acc;
}

// ============ fc4s: scan t with SRM, write out ============
__global__ __launch_bounds__(256) void k_fc4s(const float* __restrict__ I4,
                                              float* __restrict__ out) {
    int tid = threadIdx.x;
    if (tid >= 176) return;
    int b = tid / 11, o = tid - b * 11;
    float m = 0.f, s = 0.f, p = 0.f, sum = 0.f;
    for (int t = 0; t < T; t++) {
        float I = I4[(size_t)(t * 16 + b) * 11 + o];
        float spk;
        srm(m, s, p, I, spk);
        p = spk;
        sum += spk;
    }
    out[tid] = sum * 0.0625f;   // exact: integer count / 16
}

extern "C" void kernel_launch(void* const* d_in, const int* in_sizes, int n_in,
                              void* d_out, int out_size, void* d_ws, size_t ws_size,
                              hipStream_t stream) {
    const float* in = (const float*)d_in[0];
    const float* W0 = (const float*)d_in[1];
    const float* W1 = (const float*)d_in[2];
    const float* W2 = (const float*)d_in[3];
    const float* W3 = (const float*)d_in[4];
    const float* W4 = (const float*)d_in[5];
    float* out = (float*)d_out;
    char* ws = (char*)d_ws;

    size_t off = 0;
    auto alloc = [&](size_t bytes) {
        void* p = ws + off;
        off += (bytes + 255) & ~(size_t)255;
        return p;
    };
    // all buffers fully written before read each launch -> no memsets needed
    unsigned short* s0b = (unsigned short*)alloc((size_t)256 * 4096 * 64 * 2);   // 134.2 MB
    unsigned short* p1b = (unsigned short*)alloc((size_t)256 * 1024 * 128 * 2);  // 67.1 MB
    float* p2  = (float*)alloc((size_t)256 * 32768 * 4);                          // 33.6 MB
    float* I3p = (float*)alloc((size_t)256 * 8192 * 4);                           // 8.4 MB
    float* sp3 = (float*)alloc((size_t)16 * 8192 * 4);
    float* I4  = (float*)alloc((size_t)256 * 11 * 4);
    unsigned short* W1s = (unsigned short*)alloc((size_t)3 * 9 * 128 * 64 * 2);
    unsigned short* W2s = (unsigned short*)alloc((size_t)3 * 9 * 128 * 128 * 2);

    k_prep<<<(9 * 128 * 64 + 255) / 256, 256, 0, stream>>>(W1, W1s, 128, 64);
    k_prep<<<(9 * 128 * 128 + 255) / 256, 256, 0, stream>>>(W2, W2s, 128, 128);

    k_conv0T<<<16 * 8 * 8, 128, 0, stream>>>(in, W0, s0b);
    k_conv1T<<<16 * 32 * 2, 256, 0, stream>>>(s0b, W1s, p1b);
    k_conv2T<<<16 * 16 * 2, 256, 0, stream>>>(p1b, W2s, p2);
    k_fc3<<<32 * 16 * 16, 256, 0, stream>>>(p2, W3, I3p);
    k_srm3T<<<8192 / 256, 256, 0, stream>>>(I3p, sp3);
    k_fc4g<<<16, 256, 0, stream>>>(sp3, W4, I4);
    k_fc4s<<<1, 256, 0, stream>>>(I4, out);
}

// Round 8
// 2224.324 us; speedup vs baseline: 7.8772x; 1.3679x over previous
//
#include <hip/hip_runtime.h>
#include <hip/hip_bf16.h>

// SRM constants (match reference: float(np.exp(-1/16)), float(np.exp(-1/4)))
#define DM 0.9394130628134758f
#define DSC 0.7788007830714049f
#define TH 0.3f

#define B 16
#define T 16

typedef short short8 __attribute__((ext_vector_type(8)));
typedef float f32x4 __attribute__((ext_vector_type(4)));

#define SPK1 ((unsigned short)0x3F80)  // bf16 1.0

__device__ __forceinline__ void srm(float& m, float& s, float p, float I, float& spk) {
    m = DM * m * (1.f - p) + I;
    s = DSC * s * (1.f - p) + I;
    spk = (m - s > TH) ? 1.f : 0.f;
}

// ============ weight prep: fp32 OIHW -> 3-term bf16 [term][tap][co][ci] ============
__global__ __launch_bounds__(256) void k_prep(const float* __restrict__ W,
                                              unsigned short* __restrict__ Ws,
                                              int CO, int CI) {
    int idx = blockIdx.x * 256 + threadIdx.x;
    int total = CO * CI * 9;
    if (idx >= total) return;
    int tap = idx % 9, tmp = idx / 9, ci = tmp % CI, co = tmp / CI;
    float w = W[((size_t)co * CI + ci) * 9 + tap];
    __hip_bfloat16 h = __float2bfloat16(w);
    float hf = __bfloat162float(h);
    __hip_bfloat16 mdd = __float2bfloat16(w - hf);
    float mf = __bfloat162float(mdd);
    __hip_bfloat16 lo = __float2bfloat16(w - hf - mf);
    size_t base = ((size_t)tap * CO + co) * CI + ci;
    size_t stride = (size_t)9 * CO * CI;
    Ws[base] = *(unsigned short*)&h;
    Ws[base + stride] = *(unsigned short*)&mdd;
    Ws[base + 2 * stride] = *(unsigned short*)&lo;
}

// ============ conv0T: all 16 steps, state in regs -> s0b_all [t][b][y][x][64ci] bf16 ====
// grid: 16b*8yt*8cog = 1024 blocks, 128 thr.
#define S0 68
__global__ __launch_bounds__(128) void k_conv0T(const float* __restrict__ in,
                                                const float* __restrict__ W0,
                                                unsigned short* __restrict__ s0b) {
    __shared__ float tile[2][10 * S0];
    int bid = blockIdx.x;
    int cog = bid & 7, yt = (bid >> 3) & 7, b = bid >> 6;
    int tid = threadIdx.x;
    int tx = (tid & 15) * 4, ty = tid >> 4;   // ty 0..7
    int y0 = yt * 8, y = y0 + ty;

    float m[8][4] = {}, s[8][4] = {};
    unsigned pmask = 0;                        // bit c*4+j

    for (int t = 0; t < T; t++) {
        if (t) __syncthreads();
        for (int i = tid; i < 2 * 660; i += 128) {
            int cl = i / 660, rem = i - cl * 660;
            int r = rem / 66, c = rem - r * 66;
            int gy = y0 + r - 1, gx = c - 1;
            float v = 0.f;
            if ((unsigned)gy < 64u && (unsigned)gx < 64u) {
                const float* src = in + ((size_t)((b * T + t) * 2 + cl)) * 4096;
                v = fminf(fmaxf(src[gy * 64 + gx], 0.f), 1.f);
            }
            tile[cl][r * S0 + c] = v;
        }
        __syncthreads();

        float acc[8][4] = {};
#pragma unroll
        for (int cl = 0; cl < 2; cl++) {
            const float* wb = W0 + ((size_t)cog * 8 * 2 + cl) * 9;
#pragma unroll
            for (int dy = 0; dy < 3; dy++) {
                float4 A = *(const float4*)&tile[cl][(ty + dy) * S0 + tx];
                float4 Bv = *(const float4*)&tile[cl][(ty + dy) * S0 + tx + 4];
                float r0 = A.x, r1 = A.y, r2 = A.z, r3 = A.w, r4 = Bv.x, r5 = Bv.y;
#pragma unroll
                for (int c = 0; c < 8; c++) {
                    const float* w = wb + (size_t)c * 2 * 9 + dy * 3;
                    float wa = w[0], wbx = w[1], wc = w[2];
                    acc[c][0] += wa * r0 + wbx * r1 + wc * r2;
                    acc[c][1] += wa * r1 + wbx * r2 + wc * r3;
                    acc[c][2] += wa * r2 + wbx * r3 + wc * r4;
                    acc[c][3] += wa * r3 + wbx * r4 + wc * r5;
                }
            }
        }

        unsigned newmask = 0;
        unsigned short* s0p = s0b + ((size_t)(t * 16 + b) * 4096) * 64;
#pragma unroll
        for (int j = 0; j < 4; j++) {
            short8 sv;
#pragma unroll
            for (int c = 0; c < 8; c++) {
                int bit = c * 4 + j;
                float p = (pmask >> bit) & 1 ? 1.f : 0.f;
                float spk;
                srm(m[c][j], s[c][j], p, acc[c][j], spk);
                bool on = spk > 0.5f;
                if (on) newmask |= 1u << bit;
                sv[c] = on ? (short)SPK1 : (short)0;
            }
            *(short8*)(s0p + ((size_t)(y * 64 + tx + j)) * 64 + cog * 8) = sv;
        }
        pmask = newmask;
    }
}

// ============ conv1T MFMA: all t, state in regs, WEIGHTS IN LDS, fused pool ============
// grid 1024 (XCD-pinned by b), 256 thr (4 waves). Block: 16 co x 8 rows x 64 x.
// Wave: 2 rows (yo) x 4 xt x 16 co. LDS = 2kc*9tap*3tm*4q*16n short8 = 55.3 KB.
__global__ __launch_bounds__(256) void k_conv1T(const unsigned short* __restrict__ s0b,
                                                const unsigned short* __restrict__ W1s,
                                                unsigned short* __restrict__ p1b) {
    __shared__ short8 wlds[3456];
    int bid = blockIdx.x;
    int xcd = bid & 7, rest = bid >> 3;        // rest 0..127
    int b = ((rest & 1) << 3) | xcd;
    int yq = (rest >> 1) & 7;
    int cog = (rest >> 4) & 7;
    int tid = threadIdx.x;
    int lane = tid & 63, wv = tid >> 6;
    int n = lane & 15, q = lane >> 4;

    for (int idx = tid; idx < 3456; idx += 256) {
        int nn = idx & 15, qq = (idx >> 4) & 3;
        int rem = idx >> 6;                     // (kc*9+tap)*3+tm
        int tm = rem % 3, rem2 = rem / 3;
        int tap = rem2 % 9, kc = rem2 / 9;
        wlds[idx] = *(const short8*)(W1s +
            ((size_t)(tm * 9 + tap) * 128 + cog * 16 + nn) * 64 + kc * 32 + qq * 8);
    }
    __syncthreads();

    int y0w = yq * 8 + wv * 2;
    int yr = yq * 4 + wv;
    int co = cog * 16 + n;

    float sm[2][4][4] = {}, ss[2][4][4] = {};
    unsigned pmask = 0;                         // bit (yo*4+xt)*4 + r
    const short8 zf = {0, 0, 0, 0, 0, 0, 0, 0};

    for (int t = 0; t < T; t++) {
        f32x4 acc[2][4];
#pragma unroll
        for (int i = 0; i < 2; i++)
#pragma unroll
            for (int j = 0; j < 4; j++) acc[i][j] = (f32x4){0.f, 0.f, 0.f, 0.f};

        const unsigned short* sb = s0b + ((size_t)(t * 16 + b) * 4096) * 64;
#pragma unroll
        for (int kc = 0; kc < 2; kc++) {
            int cio = kc * 32 + q * 8;
#pragma unroll
            for (int dy = 0; dy < 3; dy++) {
                int gyA = y0w - 1 + dy, gyB = y0w + dy;
                bool okA = (unsigned)gyA < 64u, okB = (unsigned)gyB < 64u;
                int gyAc = min(max(gyA, 0), 63), gyBc = min(max(gyB, 0), 63);
#pragma unroll
                for (int dx = 0; dx < 3; dx++) {
                    int tap = dy * 3 + dx;
                    short8 AfA[4], AfB[4];
#pragma unroll
                    for (int xt = 0; xt < 4; xt++) {
                        int gx = xt * 16 + n + dx - 1;
                        bool okx = (unsigned)gx < 64u;
                        int gxc = min(max(gx, 0), 63);
                        short8 aA = *(const short8*)(sb + ((size_t)(gyAc * 64 + gxc)) * 64 + cio);
                        short8 aB = *(const short8*)(sb + ((size_t)(gyBc * 64 + gxc)) * 64 + cio);
                        AfA[xt] = (okA && okx) ? aA : zf;
                        AfB[xt] = (okB && okx) ? aB : zf;
                    }
#pragma unroll
                    for (int tm = 0; tm < 3; tm++) {
                        short8 Bf = wlds[((kc * 9 + tap) * 3 + tm) * 64 + q * 16 + n];
#pragma unroll
                        for (int xt = 0; xt < 4; xt++) {
                            acc[0][xt] = __builtin_amdgcn_mfma_f32_16x16x32_bf16(AfA[xt], Bf, acc[0][xt], 0, 0, 0);
                            acc[1][xt] = __builtin_amdgcn_mfma_f32_16x16x32_bf16(AfB[xt], Bf, acc[1][xt], 0, 0, 0);
                        }
                    }
                }
            }
        }

        unsigned newmask = 0;
#pragma unroll
        for (int yo = 0; yo < 2; yo++)
#pragma unroll
            for (int xt = 0; xt < 4; xt++)
#pragma unroll
                for (int r = 0; r < 4; r++) {
                    int bit = (yo * 4 + xt) * 4 + r;
                    float p = (pmask >> bit) & 1 ? 1.f : 0.f;
                    float spk;
                    srm(sm[yo][xt][r], ss[yo][xt][r], p, acc[yo][xt][r], spk);
                    if (spk > 0.5f) newmask |= 1u << bit;
                }
        pmask = newmask;

        unsigned short* pb = p1b + (((size_t)(t * 16 + b) * 1024) + yr * 32) * 128 + co;
#pragma unroll
        for (int xt = 0; xt < 4; xt++)
#pragma unroll
            for (int rp = 0; rp < 2; rp++) {
                int i0 = (0 * 4 + xt) * 4 + 2 * rp;
                int i1 = (1 * 4 + xt) * 4 + 2 * rp;
                unsigned on = ((newmask >> i0) | (newmask >> (i0 + 1)) |
                               (newmask >> i1) | (newmask >> (i1 + 1))) & 1u;
                int xp = xt * 8 + q * 2 + rp;
                pb[(size_t)xp * 128] = on ? SPK1 : (unsigned short)0;
            }
    }
}

// ============ conv2T MFMA: all t, state in regs, WEIGHTS IN LDS, fused pool ============
// grid 512 (XCD-pinned by b), 256 thr. Block: 16 co x 8 rows x 32 x.
// Wave: 2 rows x 2 xt x 16 co. LDS = 4kc*9*3*4*16 short8 = 110.6 KB (gfx950: 160 KB/WG).
__global__ __launch_bounds__(256) void k_conv2T(const unsigned short* __restrict__ p1b,
                                                const unsigned short* __restrict__ W2s,
                                                float* __restrict__ p2) {
    __shared__ short8 wlds[6912];
    int bid = blockIdx.x;
    int xcd = bid & 7, rest = bid >> 3;        // rest 0..63
    int b = ((rest & 1) << 3) | xcd;
    int yq = (rest >> 1) & 3;
    int cog = (rest >> 3) & 7;
    int tid = threadIdx.x;
    int lane = tid & 63, wv = tid >> 6;
    int n = lane & 15, q = lane >> 4;

    for (int idx = tid; idx < 6912; idx += 256) {
        int nn = idx & 15, qq = (idx >> 4) & 3;
        int rem = idx >> 6;                     // (kc*9+tap)*3+tm
        int tm = rem % 3, rem2 = rem / 3;
        int tap = rem2 % 9, kc = rem2 / 9;
        wlds[idx] = *(const short8*)(W2s +
            ((size_t)(tm * 9 + tap) * 128 + cog * 16 + nn) * 128 + kc * 32 + qq * 8);
    }
    __syncthreads();

    int y0w = yq * 8 + wv * 2;
    int yr = yq * 4 + wv;
    int co = cog * 16 + n;

    float sm[2][2][4] = {}, ss[2][2][4] = {};
    unsigned pmask = 0;                         // bit (yo*2+xt)*4 + r
    const short8 zf = {0, 0, 0, 0, 0, 0, 0, 0};

    for (int t = 0; t < T; t++) {
        f32x4 acc[2][2];
#pragma unroll
        for (int i = 0; i < 2; i++)
#pragma unroll
            for (int j = 0; j < 2; j++) acc[i][j] = (f32x4){0.f, 0.f, 0.f, 0.f};

        const unsigned short* sb = p1b + ((size_t)(t * 16 + b) * 1024) * 128;
#pragma unroll
        for (int kc = 0; kc < 4; kc++) {
            int cio = kc * 32 + q * 8;
#pragma unroll
            for (int dy = 0; dy < 3; dy++) {
                int gyA = y0w - 1 + dy, gyB = y0w + dy;
                bool okA = (unsigned)gyA < 32u, okB = (unsigned)gyB < 32u;
                int gyAc = min(max(gyA, 0), 31), gyBc = min(max(gyB, 0), 31);
#pragma unroll
                for (int dx = 0; dx < 3; dx++) {
                    int tap = dy * 3 + dx;
                    short8 AfA[2], AfB[2];
#pragma unroll
                    for (int xt = 0; xt < 2; xt++) {
                        int gx = xt * 16 + n + dx - 1;
                        bool okx = (unsigned)gx < 32u;
                        int gxc = min(max(gx, 0), 31);
                        short8 aA = *(const short8*)(sb + ((size_t)(gyAc * 32 + gxc)) * 128 + cio);
                        short8 aB = *(const short8*)(sb + ((size_t)(gyBc * 32 + gxc)) * 128 + cio);
                        AfA[xt] = (okA && okx) ? aA : zf;
                        AfB[xt] = (okB && okx) ? aB : zf;
                    }
#pragma unroll
                    for (int tm = 0; tm < 3; tm++) {
                        short8 Bf = wlds[((kc * 9 + tap) * 3 + tm) * 64 + q * 16 + n];
#pragma unroll
                        for (int xt = 0; xt < 2; xt++) {
                            acc[0][xt] = __builtin_amdgcn_mfma_f32_16x16x32_bf16(AfA[xt], Bf, acc[0][xt], 0, 0, 0);
                            acc[1][xt] = __builtin_amdgcn_mfma_f32_16x16x32_bf16(AfB[xt], Bf, acc[1][xt], 0, 0, 0);
                        }
                    }
                }
            }
        }

        unsigned newmask = 0;
#pragma unroll
        for (int yo = 0; yo < 2; yo++)
#pragma unroll
            for (int xt = 0; xt < 2; xt++)
#pragma unroll
                for (int r = 0; r < 4; r++) {
                    int bit = (yo * 2 + xt) * 4 + r;
                    float p = (pmask >> bit) & 1 ? 1.f : 0.f;
                    float spk;
                    srm(sm[yo][xt][r], ss[yo][xt][r], p, acc[yo][xt][r], spk);
                    if (spk > 0.5f) newmask |= 1u << bit;
                }
        pmask = newmask;

        float* pp = p2 + (size_t)(t * 16 + b) * 32768 + (size_t)co * 256 + yr * 16;
#pragma unroll
        for (int xt = 0; xt < 2; xt++)
#pragma unroll
            for (int rp = 0; rp < 2; rp++) {
                int i0 = (0 * 2 + xt) * 4 + 2 * rp;
                int i1 = (1 * 2 + xt) * 4 + 2 * rp;
                unsigned on = ((newmask >> i0) | (newmask >> (i0 + 1)) |
                               (newmask >> i1) | (newmask >> (i1 + 1))) & 1u;
                int xp = xt * 8 + q * 2 + rp;
                pp[xp] = on ? 1.f : 0.f;
            }
    }
}

// ============ fc3: per-t grid. p2[t][16,32768] @ W3^T -> I3p[t][ks][8192] ============
// grid 8192 = 32 ot x 16 ks x 16 t; block 256 (4 waves). Wave: 4 o x 16 b, lanes along k.
__global__ __launch_bounds__(256) void k_fc3(const float* __restrict__ p2,
                                             const float* __restrict__ W3,
                                             float* __restrict__ I3p) {
    int ot = blockIdx.x & 31, ks = (blockIdx.x >> 5) & 15, t = blockIdx.x >> 9;
    int lane = threadIdx.x & 63, wv = threadIdx.x >> 6;
    int o0 = ot * 16 + wv * 4;
    int kb = ks * 2048 + lane * 4;

    float acc[4][16];
#pragma unroll
    for (int o = 0; o < 4; o++)
#pragma unroll
        for (int bb = 0; bb < 16; bb++) acc[o][bb] = 0.f;

#pragma unroll
    for (int kk = 0; kk < 8; kk++) {
        int k = kb + kk * 256;
        float4 w4[4];
#pragma unroll
        for (int o = 0; o < 4; o++)
            w4[o] = *(const float4*)(W3 + (size_t)(o0 + o) * 32768 + k);
#pragma unroll
        for (int bb = 0; bb < 16; bb++) {
            float4 pv = *(const float4*)(p2 + (size_t)(t * 16 + bb) * 32768 + k);
#pragma unroll
            for (int o = 0; o < 4; o++)
                acc[o][bb] += w4[o].x * pv.x + w4[o].y * pv.y +
                              w4[o].z * pv.z + w4[o].w * pv.w;
        }
    }
#pragma unroll
    for (int o = 0; o < 4; o++)
#pragma unroll
        for (int bb = 0; bb < 16; bb++)
#pragma unroll
            for (int d = 1; d < 64; d <<= 1)
                acc[o][bb] += __shfl_xor(acc[o][bb], d);

    int bb = lane & 15, osl = lane >> 4;
    float v = 0.f;
#pragma unroll
    for (int o = 0; o < 4; o++)
#pragma unroll
        for (int b2 = 0; b2 < 16; b2++)
            if (osl == o && bb == b2) v = acc[o][b2];
    I3p[((size_t)(t * 16 + ks)) * 8192 + bb * 512 + o0 + osl] = v;
}

// ============ srm3T: per neuron, scan t: reduce 16 partials + SRM -> sp3_all [t][8192]
__global__ __launch_bounds__(256) void k_srm3T(const float* __restrict__ I3p,
                                               float* __restrict__ sp3) {
    int idx = blockIdx.x * 256 + threadIdx.x;    // 8192
    float m = 0.f, s = 0.f, p = 0.f;
    for (int t = 0; t < T; t++) {
        float I = 0.f;
#pragma unroll
        for (int ks = 0; ks < 16; ks++) I += I3p[((size_t)(t * 16 + ks)) * 8192 + idx];
        float spk;
        srm(m, s, p, I, spk);
        p = spk;
        sp3[t * 8192 + idx] = spk;
    }
}

// ============ fc4g: I4[t*16+b][11] = sp3[t][b] @ W4^T ============
__global__ __launch_bounds__(256) void k_fc4g(const float* __restrict__ sp3,
                                              const float* __restrict__ W4,
                                              float* __restrict__ I4) {
    int t = blockIdx.x, tid = threadIdx.x;
    if (tid >= 176) return;
    int b = tid / 11, o = tid - b * 11;
    const float4* a = (const float4*)(sp3 + (size_t)t * 8192 + b * 512);
    const float4* w = (const float4*)(W4 + o * 512);
    float acc = 0.f;
    for (int k = 0; k < 128; k++) {
        float4 x = a[k], y = w[k];
        acc += x.x * y.x + x.y * y.y + x.z * y.z + x.w * y.w;
    }
    I4[(size_t)(t * 16 + b) * 11 + o] = acc;
}

// ============ fc4s: scan t with SRM, write out ============
__global__ __launch_bounds__(256) void k_fc4s(const float* __restrict__ I4,
                                              float* __restrict__ out) {
    int tid = threadIdx.x;
    if (tid >= 176) return;
    int b = tid / 11, o = tid - b * 11;
    float m = 0.f, s = 0.f, p = 0.f, sum = 0.f;
    for (int t = 0; t < T; t++) {
        float I = I4[(size_t)(t * 16 + b) * 11 + o];
        float spk;
        srm(m, s, p, I, spk);
        p = spk;
        sum += spk;
    }
    out[tid] = sum * 0.0625f;   // exact: integer count / 16
}

extern "C" void kernel_launch(void* const* d_in, const int* in_sizes, int n_in,
                              void* d_out, int out_size, void* d_ws, size_t ws_size,
                              hipStream_t stream) {
    const float* in = (const float*)d_in[0];
    const float* W0 = (const float*)d_in[1];
    const float* W1 = (const float*)d_in[2];
    const float* W2 = (const float*)d_in[3];
    const float* W3 = (const float*)d_in[4];
    const float* W4 = (const float*)d_in[5];
    float* out = (float*)d_out;
    char* ws = (char*)d_ws;

    size_t off = 0;
    auto alloc = [&](size_t bytes) {
        void* p = ws + off;
        off += (bytes + 255) & ~(size_t)255;
        return p;
    };
    // all buffers fully written before read each launch -> no memsets needed
    unsigned short* s0b = (unsigned short*)alloc((size_t)256 * 4096 * 64 * 2);   // 134.2 MB
    unsigned short* p1b = (unsigned short*)alloc((size_t)256 * 1024 * 128 * 2);  // 67.1 MB
    float* p2  = (float*)alloc((size_t)256 * 32768 * 4);                          // 33.6 MB
    float* I3p = (float*)alloc((size_t)256 * 8192 * 4);                           // 8.4 MB
    float* sp3 = (float*)alloc((size_t)16 * 8192 * 4);
    float* I4  = (float*)alloc((size_t)256 * 11 * 4);
    unsigned short* W1s = (unsigned short*)alloc((size_t)3 * 9 * 128 * 64 * 2);
    unsigned short* W2s = (unsigned short*)alloc((size_t)3 * 9 * 128 * 128 * 2);

    k_prep<<<(9 * 128 * 64 + 255) / 256, 256, 0, stream>>>(W1, W1s, 128, 64);
    k_prep<<<(9 * 128 * 128 + 255) / 256, 256, 0, stream>>>(W2, W2s, 128, 128);

    k_conv0T<<<16 * 8 * 8, 128, 0, stream>>>(in, W0, s0b);
    k_conv1T<<<1024, 256, 0, stream>>>(s0b, W1s, p1b);
    k_conv2T<<<512, 256, 0, stream>>>(p1b, W2s, p2);
    k_fc3<<<32 * 16 * 16, 256, 0, stream>>>(p2, W3, I3p);
    k_srm3T<<<8192 / 256, 256, 0, stream>>>(I3p, sp3);
    k_fc4g<<<16, 256, 0, stream>>>(sp3, W4, I4);
    k_fc4s<<<1, 256, 0, stream>>>(I4, out);
}

// Round 9
// 1948.273 us; speedup vs baseline: 8.9934x; 1.1417x over previous
//
#include <hip/hip_runtime.h>
#include <hip/hip_bf16.h>

// SRM constants (match reference: float(np.exp(-1/16)), float(np.exp(-1/4)))
#define DM 0.9394130628134758f
#define DSC 0.7788007830714049f
#define TH 0.3f

#define B 16
#define T 16

typedef short short8 __attribute__((ext_vector_type(8)));
typedef float f32x4 __attribute__((ext_vector_type(4)));

#define SPK1 ((unsigned short)0x3F80)  // bf16 1.0

__device__ __forceinline__ void srm(float& m, float& s, float p, float I, float& spk) {
    m = DM * m * (1.f - p) + I;
    s = DSC * s * (1.f - p) + I;
    spk = (m - s > TH) ? 1.f : 0.f;
}

// ============ weight prep: fp32 OIHW -> 3-term bf16 [term][tap][co][ci] ============
__global__ __launch_bounds__(256) void k_prep(const float* __restrict__ W,
                                              unsigned short* __restrict__ Ws,
                                              int CO, int CI) {
    int idx = blockIdx.x * 256 + threadIdx.x;
    int total = CO * CI * 9;
    if (idx >= total) return;
    int tap = idx % 9, tmp = idx / 9, ci = tmp % CI, co = tmp / CI;
    float w = W[((size_t)co * CI + ci) * 9 + tap];
    __hip_bfloat16 h = __float2bfloat16(w);
    float hf = __bfloat162float(h);
    __hip_bfloat16 mdd = __float2bfloat16(w - hf);
    float mf = __bfloat162float(mdd);
    __hip_bfloat16 lo = __float2bfloat16(w - hf - mf);
    size_t base = ((size_t)tap * CO + co) * CI + ci;
    size_t stride = (size_t)9 * CO * CI;
    Ws[base] = *(unsigned short*)&h;
    Ws[base + stride] = *(unsigned short*)&mdd;
    Ws[base + 2 * stride] = *(unsigned short*)&lo;
}

// ============ conv0T: all 16 steps, state in regs -> s0b_all [t][b][y][x][64ci] bf16 ====
// grid: 16b*8yt*8cog = 1024 blocks, 128 thr.
#define S0 68
__global__ __launch_bounds__(128) void k_conv0T(const float* __restrict__ in,
                                                const float* __restrict__ W0,
                                                unsigned short* __restrict__ s0b) {
    __shared__ float tile[2][10 * S0];
    int bid = blockIdx.x;
    int cog = bid & 7, yt = (bid >> 3) & 7, b = bid >> 6;
    int tid = threadIdx.x;
    int tx = (tid & 15) * 4, ty = tid >> 4;   // ty 0..7
    int y0 = yt * 8, y = y0 + ty;

    float m[8][4] = {}, s[8][4] = {};
    unsigned pmask = 0;                        // bit c*4+j

    for (int t = 0; t < T; t++) {
        if (t) __syncthreads();
        for (int i = tid; i < 2 * 660; i += 128) {
            int cl = i / 660, rem = i - cl * 660;
            int r = rem / 66, c = rem - r * 66;
            int gy = y0 + r - 1, gx = c - 1;
            float v = 0.f;
            if ((unsigned)gy < 64u && (unsigned)gx < 64u) {
                const float* src = in + ((size_t)((b * T + t) * 2 + cl)) * 4096;
                v = fminf(fmaxf(src[gy * 64 + gx], 0.f), 1.f);
            }
            tile[cl][r * S0 + c] = v;
        }
        __syncthreads();

        float acc[8][4] = {};
#pragma unroll
        for (int cl = 0; cl < 2; cl++) {
            const float* wb = W0 + ((size_t)cog * 8 * 2 + cl) * 9;
#pragma unroll
            for (int dy = 0; dy < 3; dy++) {
                float4 A = *(const float4*)&tile[cl][(ty + dy) * S0 + tx];
                float4 Bv = *(const float4*)&tile[cl][(ty + dy) * S0 + tx + 4];
                float r0 = A.x, r1 = A.y, r2 = A.z, r3 = A.w, r4 = Bv.x, r5 = Bv.y;
#pragma unroll
                for (int c = 0; c < 8; c++) {
                    const float* w = wb + (size_t)c * 2 * 9 + dy * 3;
                    float wa = w[0], wbx = w[1], wc = w[2];
                    acc[c][0] += wa * r0 + wbx * r1 + wc * r2;
                    acc[c][1] += wa * r1 + wbx * r2 + wc * r3;
                    acc[c][2] += wa * r2 + wbx * r3 + wc * r4;
                    acc[c][3] += wa * r3 + wbx * r4 + wc * r5;
                }
            }
        }

        unsigned newmask = 0;
        unsigned short* s0p = s0b + ((size_t)(t * 16 + b) * 4096) * 64;
#pragma unroll
        for (int j = 0; j < 4; j++) {
            short8 sv;
#pragma unroll
            for (int c = 0; c < 8; c++) {
                int bit = c * 4 + j;
                float p = (pmask >> bit) & 1 ? 1.f : 0.f;
                float spk;
                srm(m[c][j], s[c][j], p, acc[c][j], spk);
                bool on = spk > 0.5f;
                if (on) newmask |= 1u << bit;
                sv[c] = on ? (short)SPK1 : (short)0;
            }
            *(short8*)(s0p + ((size_t)(y * 64 + tx + j)) * 64 + cog * 8) = sv;
        }
        pmask = newmask;
    }
}

// ============ conv1T MFMA: all t, state in regs, WEIGHTS + A-TILE IN LDS, fused pool ====
// grid 1024 (XCD-pinned by b), 256 thr (4 waves). Block: 16 co x 8 rows x 64 x.
// LDS: A-tile 10 rows x 64 x x 64 ci (swizzled) = 80 KB + weights 54 KB = 134 KB -> 1 blk/CU.
#define A1CH 5120   // 10*64*8 short8 chunks
#define W1CH 3456
__global__ __launch_bounds__(256, 1) void k_conv1T(const unsigned short* __restrict__ s0b,
                                                   const unsigned short* __restrict__ W1s,
                                                   unsigned short* __restrict__ p1b) {
    __shared__ short8 atile[A1CH];
    __shared__ short8 wlds[W1CH];
    int bid = blockIdx.x;
    int xcd = bid & 7, rest = bid >> 3;        // rest 0..127
    int b = ((rest & 1) << 3) | xcd;
    int yq = (rest >> 1) & 7;
    int cog = (rest >> 4) & 7;
    int tid = threadIdx.x;
    int lane = tid & 63, wv = tid >> 6;
    int n = lane & 15, q = lane >> 4;

    for (int idx = tid; idx < W1CH; idx += 256) {
        int nn = idx & 15, qq = (idx >> 4) & 3;
        int rem = idx >> 6;                     // (kc*9+tap)*3+tm
        int tm = rem % 3, rem2 = rem / 3;
        int tap = rem2 % 9, kc = rem2 / 9;
        wlds[idx] = *(const short8*)(W1s +
            ((size_t)(tm * 9 + tap) * 128 + cog * 16 + nn) * 64 + kc * 32 + qq * 8);
    }

    int y0 = yq * 8;
    int y0w = y0 + wv * 2;
    int yr = yq * 4 + wv;
    int co = cog * 16 + n;

    float sm[2][4][4] = {}, ss[2][4][4] = {};
    unsigned pmask = 0;                         // bit (yo*4+xt)*4 + r
    const short8 zf = {0, 0, 0, 0, 0, 0, 0, 0};

    for (int t = 0; t < T; t++) {
        __syncthreads();   // atile/wlds safe to (re)write / first use
        const unsigned short* sb = s0b + ((size_t)(t * 16 + b) * 4096) * 64;
        // stage A-tile: local row r = global row y0-1+r (clamped; OOB masked in compute)
        // swizzle: chunk c stored at c ^ (x&7) to break 128B-stride bank aliasing
        for (int i = tid; i < A1CH; i += 256) {
            int c = i & 7, x = (i >> 3) & 63, r = i >> 9;
            int gy = min(max(y0 - 1 + r, 0), 63);
            short8 v = *(const short8*)(sb + ((size_t)(gy * 64 + x)) * 64 + c * 8);
            atile[((r * 64 + x) << 3) + (c ^ (x & 7))] = v;
        }
        __syncthreads();

        f32x4 acc[2][4];
#pragma unroll
        for (int i = 0; i < 2; i++)
#pragma unroll
            for (int j = 0; j < 4; j++) acc[i][j] = (f32x4){0.f, 0.f, 0.f, 0.f};

#pragma unroll
        for (int kc = 0; kc < 2; kc++) {
#pragma unroll
            for (int dy = 0; dy < 3; dy++) {
                int gyA = y0w - 1 + dy, gyB = y0w + dy;
                bool okA = (unsigned)gyA < 64u, okB = (unsigned)gyB < 64u;
                int rA = wv * 2 + dy, rB = rA + 1;   // local tile rows
#pragma unroll
                for (int dx = 0; dx < 3; dx++) {
                    int tap = dy * 3 + dx;
                    short8 AfA[4], AfB[4];
#pragma unroll
                    for (int xt = 0; xt < 4; xt++) {
                        int gx = xt * 16 + n + dx - 1;
                        bool okx = (unsigned)gx < 64u;
                        int gxc = min(max(gx, 0), 63);
                        int cs = (kc * 4 + q) ^ (gxc & 7);
                        short8 aA = atile[((rA * 64 + gxc) << 3) + cs];
                        short8 aB = atile[((rB * 64 + gxc) << 3) + cs];
                        AfA[xt] = (okA && okx) ? aA : zf;
                        AfB[xt] = (okB && okx) ? aB : zf;
                    }
#pragma unroll
                    for (int tm = 0; tm < 3; tm++) {
                        short8 Bf = wlds[((kc * 9 + tap) * 3 + tm) * 64 + q * 16 + n];
#pragma unroll
                        for (int xt = 0; xt < 4; xt++) {
                            acc[0][xt] = __builtin_amdgcn_mfma_f32_16x16x32_bf16(AfA[xt], Bf, acc[0][xt], 0, 0, 0);
                            acc[1][xt] = __builtin_amdgcn_mfma_f32_16x16x32_bf16(AfB[xt], Bf, acc[1][xt], 0, 0, 0);
                        }
                    }
                }
            }
        }

        unsigned newmask = 0;
#pragma unroll
        for (int yo = 0; yo < 2; yo++)
#pragma unroll
            for (int xt = 0; xt < 4; xt++)
#pragma unroll
                for (int r = 0; r < 4; r++) {
                    int bit = (yo * 4 + xt) * 4 + r;
                    float p = (pmask >> bit) & 1 ? 1.f : 0.f;
                    float spk;
                    srm(sm[yo][xt][r], ss[yo][xt][r], p, acc[yo][xt][r], spk);
                    if (spk > 0.5f) newmask |= 1u << bit;
                }
        pmask = newmask;

        unsigned short* pb = p1b + (((size_t)(t * 16 + b) * 1024) + yr * 32) * 128 + co;
#pragma unroll
        for (int xt = 0; xt < 4; xt++)
#pragma unroll
            for (int rp = 0; rp < 2; rp++) {
                int i0 = (0 * 4 + xt) * 4 + 2 * rp;
                int i1 = (1 * 4 + xt) * 4 + 2 * rp;
                unsigned on = ((newmask >> i0) | (newmask >> (i0 + 1)) |
                               (newmask >> i1) | (newmask >> (i1 + 1))) & 1u;
                int xp = xt * 8 + q * 2 + rp;
                pb[(size_t)xp * 128] = on ? SPK1 : (unsigned short)0;
            }
    }
}

// ============ conv2T MFMA: all t, state in regs, WEIGHTS IN LDS, fused pool ============
// grid 512 (XCD-pinned by b), 256 thr. Block: 16 co x 8 rows x 32 x.
// Wave: 2 rows x 2 xt x 16 co. LDS = 4kc*9*3*4*16 short8 = 110.6 KB (gfx950: 160 KB/WG).
__global__ __launch_bounds__(256) void k_conv2T(const unsigned short* __restrict__ p1b,
                                                const unsigned short* __restrict__ W2s,
                                                float* __restrict__ p2) {
    __shared__ short8 wlds[6912];
    int bid = blockIdx.x;
    int xcd = bid & 7, rest = bid >> 3;        // rest 0..63
    int b = ((rest & 1) << 3) | xcd;
    int yq = (rest >> 1) & 3;
    int cog = (rest >> 3) & 7;
    int tid = threadIdx.x;
    int lane = tid & 63, wv = tid >> 6;
    int n = lane & 15, q = lane >> 4;

    for (int idx = tid; idx < 6912; idx += 256) {
        int nn = idx & 15, qq = (idx >> 4) & 3;
        int rem = idx >> 6;                     // (kc*9+tap)*3+tm
        int tm = rem % 3, rem2 = rem / 3;
        int tap = rem2 % 9, kc = rem2 / 9;
        wlds[idx] = *(const short8*)(W2s +
            ((size_t)(tm * 9 + tap) * 128 + cog * 16 + nn) * 128 + kc * 32 + qq * 8);
    }
    __syncthreads();

    int y0w = yq * 8 + wv * 2;
    int yr = yq * 4 + wv;
    int co = cog * 16 + n;

    float sm[2][2][4] = {}, ss[2][2][4] = {};
    unsigned pmask = 0;                         // bit (yo*2+xt)*4 + r
    const short8 zf = {0, 0, 0, 0, 0, 0, 0, 0};

    for (int t = 0; t < T; t++) {
        f32x4 acc[2][2];
#pragma unroll
        for (int i = 0; i < 2; i++)
#pragma unroll
            for (int j = 0; j < 2; j++) acc[i][j] = (f32x4){0.f, 0.f, 0.f, 0.f};

        const unsigned short* sb = p1b + ((size_t)(t * 16 + b) * 1024) * 128;
#pragma unroll
        for (int kc = 0; kc < 4; kc++) {
            int cio = kc * 32 + q * 8;
#pragma unroll
            for (int dy = 0; dy < 3; dy++) {
                int gyA = y0w - 1 + dy, gyB = y0w + dy;
                bool okA = (unsigned)gyA < 32u, okB = (unsigned)gyB < 32u;
                int gyAc = min(max(gyA, 0), 31), gyBc = min(max(gyB, 0), 31);
#pragma unroll
                for (int dx = 0; dx < 3; dx++) {
                    int tap = dy * 3 + dx;
                    short8 AfA[2], AfB[2];
#pragma unroll
                    for (int xt = 0; xt < 2; xt++) {
                        int gx = xt * 16 + n + dx - 1;
                        bool okx = (unsigned)gx < 32u;
                        int gxc = min(max(gx, 0), 31);
                        short8 aA = *(const short8*)(sb + ((size_t)(gyAc * 32 + gxc)) * 128 + cio);
                        short8 aB = *(const short8*)(sb + ((size_t)(gyBc * 32 + gxc)) * 128 + cio);
                        AfA[xt] = (okA && okx) ? aA : zf;
                        AfB[xt] = (okB && okx) ? aB : zf;
                    }
#pragma unroll
                    for (int tm = 0; tm < 3; tm++) {
                        short8 Bf = wlds[((kc * 9 + tap) * 3 + tm) * 64 + q * 16 + n];
#pragma unroll
                        for (int xt = 0; xt < 2; xt++) {
                            acc[0][xt] = __builtin_amdgcn_mfma_f32_16x16x32_bf16(AfA[xt], Bf, acc[0][xt], 0, 0, 0);
                            acc[1][xt] = __builtin_amdgcn_mfma_f32_16x16x32_bf16(AfB[xt], Bf, acc[1][xt], 0, 0, 0);
                        }
                    }
                }
            }
        }

        unsigned newmask = 0;
#pragma unroll
        for (int yo = 0; yo < 2; yo++)
#pragma unroll
            for (int xt = 0; xt < 2; xt++)
#pragma unroll
                for (int r = 0; r < 4; r++) {
                    int bit = (yo * 2 + xt) * 4 + r;
                    float p = (pmask >> bit) & 1 ? 1.f : 0.f;
                    float spk;
                    srm(sm[yo][xt][r], ss[yo][xt][r], p, acc[yo][xt][r], spk);
                    if (spk > 0.5f) newmask |= 1u << bit;
                }
        pmask = newmask;

        float* pp = p2 + (size_t)(t * 16 + b) * 32768 + (size_t)co * 256 + yr * 16;
#pragma unroll
        for (int xt = 0; xt < 2; xt++)
#pragma unroll
            for (int rp = 0; rp < 2; rp++) {
                int i0 = (0 * 2 + xt) * 4 + 2 * rp;
                int i1 = (1 * 2 + xt) * 4 + 2 * rp;
                unsigned on = ((newmask >> i0) | (newmask >> (i0 + 1)) |
                               (newmask >> i1) | (newmask >> (i1 + 1))) & 1u;
                int xp = xt * 8 + q * 2 + rp;
                pp[xp] = on ? 1.f : 0.f;
            }
    }
}

// ============ fc3: per-t grid. p2[t][16,32768] @ W3^T -> I3p[t][ks][8192] ============
// grid 8192 = 32 ot x 16 ks x 16 t; block 256 (4 waves). Wave: 4 o x 16 b, lanes along k.
__global__ __launch_bounds__(256) void k_fc3(const float* __restrict__ p2,
                                             const float* __restrict__ W3,
                                             float* __restrict__ I3p) {
    int ot = blockIdx.x & 31, ks = (blockIdx.x >> 5) & 15, t = blockIdx.x >> 9;
    int lane = threadIdx.x & 63, wv = threadIdx.x >> 6;
    int o0 = ot * 16 + wv * 4;
    int kb = ks * 2048 + lane * 4;

    float acc[4][16];
#pragma unroll
    for (int o = 0; o < 4; o++)
#pragma unroll
        for (int bb = 0; bb < 16; bb++) acc[o][bb] = 0.f;

#pragma unroll
    for (int kk = 0; kk < 8; kk++) {
        int k = kb + kk * 256;
        float4 w4[4];
#pragma unroll
        for (int o = 0; o < 4; o++)
            w4[o] = *(const float4*)(W3 + (size_t)(o0 + o) * 32768 + k);
#pragma unroll
        for (int bb = 0; bb < 16; bb++) {
            float4 pv = *(const float4*)(p2 + (size_t)(t * 16 + bb) * 32768 + k);
#pragma unroll
            for (int o = 0; o < 4; o++)
                acc[o][bb] += w4[o].x * pv.x + w4[o].y * pv.y +
                              w4[o].z * pv.z + w4[o].w * pv.w;
        }
    }
#pragma unroll
    for (int o = 0; o < 4; o++)
#pragma unroll
        for (int bb = 0; bb < 16; bb++)
#pragma unroll
            for (int d = 1; d < 64; d <<= 1)
                acc[o][bb] += __shfl_xor(acc[o][bb], d);

    int bb = lane & 15, osl = lane >> 4;
    float v = 0.f;
#pragma unroll
    for (int o = 0; o < 4; o++)
#pragma unroll
        for (int b2 = 0; b2 < 16; b2++)
            if (osl == o && bb == b2) v = acc[o][b2];
    I3p[((size_t)(t * 16 + ks)) * 8192 + bb * 512 + o0 + osl] = v;
}

// ============ srm3T: per neuron, scan t: reduce 16 partials + SRM -> sp3_all [t][8192]
__global__ __launch_bounds__(256) void k_srm3T(const float* __restrict__ I3p,
                                               float* __restrict__ sp3) {
    int idx = blockIdx.x * 256 + threadIdx.x;    // 8192
    float m = 0.f, s = 0.f, p = 0.f;
    for (int t = 0; t < T; t++) {
        float I = 0.f;
#pragma unroll
        for (int ks = 0; ks < 16; ks++) I += I3p[((size_t)(t * 16 + ks)) * 8192 + idx];
        float spk;
        srm(m, s, p, I, spk);
        p = spk;
        sp3[t * 8192 + idx] = spk;
    }
}

// ============ fc4g: I4[t*16+b][11] = sp3[t][b] @ W4^T ============
__global__ __launch_bounds__(256) void k_fc4g(const float* __restrict__ sp3,
                                              const float* __restrict__ W4,
                                              float* __restrict__ I4) {
    int t = blockIdx.x, tid = threadIdx.x;
    if (tid >= 176) return;
    int b = tid / 11, o = tid - b * 11;
    const float4* a = (const float4*)(sp3 + (size_t)t * 8192 + b * 512);
    const float4* w = (const float4*)(W4 + o * 512);
    float acc = 0.f;
    for (int k = 0; k < 128; k++) {
        float4 x = a[k], y = w[k];
        acc += x.x * y.x + x.y * y.y + x.z * y.z + x.w * y.w;
    }
    I4[(size_t)(t * 16 + b) * 11 + o] = acc;
}

// ============ fc4s: scan t with SRM, write out ============
__global__ __launch_bounds__(256) void k_fc4s(const float* __restrict__ I4,
                                              float* __restrict__ out) {
    int tid = threadIdx.x;
    if (tid >= 176) return;
    int b = tid / 11, o = tid - b * 11;
    float m = 0.f, s = 0.f, p = 0.f, sum = 0.f;
    for (int t = 0; t < T; t++) {
        float I = I4[(size_t)(t * 16 + b) * 11 + o];
        float spk;
        srm(m, s, p, I, spk);
        p = spk;
        sum += spk;
    }
    out[tid] = sum * 0.0625f;   // exact: integer count / 16
}

extern "C" void kernel_launch(void* const* d_in, const int* in_sizes, int n_in,
                              void* d_out, int out_size, void* d_ws, size_t ws_size,
                              hipStream_t stream) {
    const float* in = (const float*)d_in[0];
    const float* W0 = (const float*)d_in[1];
    const float* W1 = (const float*)d_in[2];
    const float* W2 = (const float*)d_in[3];
    const float* W3 = (const float*)d_in[4];
    const float* W4 = (const float*)d_in[5];
    float* out = (float*)d_out;
    char* ws = (char*)d_ws;

    size_t off = 0;
    auto alloc = [&](size_t bytes) {
        void* p = ws + off;
        off += (bytes + 255) & ~(size_t)255;
        return p;
    };
    // all buffers fully written before read each launch -> no memsets needed
    unsigned short* s0b = (unsigned short*)alloc((size_t)256 * 4096 * 64 * 2);   // 134.2 MB
    unsigned short* p1b = (unsigned short*)alloc((size_t)256 * 1024 * 128 * 2);  // 67.1 MB
    float* p2  = (float*)alloc((size_t)256 * 32768 * 4);                          // 33.6 MB
    float* I3p = (float*)alloc((size_t)256 * 8192 * 4);                           // 8.4 MB
    float* sp3 = (float*)alloc((size_t)16 * 8192 * 4);
    float* I4  = (float*)alloc((size_t)256 * 11 * 4);
    unsigned short* W1s = (unsigned short*)alloc((size_t)3 * 9 * 128 * 64 * 2);
    unsigned short* W2s = (unsigned short*)alloc((size_t)3 * 9 * 128 * 128 * 2);

    k_prep<<<(9 * 128 * 64 + 255) / 256, 256, 0, stream>>>(W1, W1s, 128, 64);
    k_prep<<<(9 * 128 * 128 + 255) / 256, 256, 0, stream>>>(W2, W2s, 128, 128);

    k_conv0T<<<16 * 8 * 8, 128, 0, stream>>>(in, W0, s0b);
    k_conv1T<<<1024, 256, 0, stream>>>(s0b, W1s, p1b);
    k_conv2T<<<512, 256, 0, stream>>>(p1b, W2s, p2);
    k_fc3<<<32 * 16 * 16, 256, 0, stream>>>(p2, W3, I3p);
    k_srm3T<<<8192 / 256, 256, 0, stream>>>(I3p, sp3);
    k_fc4g<<<16, 256, 0, stream>>>(sp3, W4, I4);
    k_fc4s<<<1, 256, 0, stream>>>(I4, out);
}

// Round 10
// 1598.806 us; speedup vs baseline: 10.9591x; 1.2186x over previous
//
#include <hip/hip_runtime.h>
#include <hip/hip_bf16.h>

// SRM constants (match reference: float(np.exp(-1/16)), float(np.exp(-1/4)))
#define DM 0.9394130628134758f
#define DSC 0.7788007830714049f
#define TH 0.3f

#define B 16
#define T 16

typedef short short8 __attribute__((ext_vector_type(8)));
typedef float f32x4 __attribute__((ext_vector_type(4)));

#define SPK1 ((unsigned short)0x3F80)  // bf16 1.0

__device__ __forceinline__ void srm(float& m, float& s, float p, float I, float& spk) {
    m = DM * m * (1.f - p) + I;
    s = DSC * s * (1.f - p) + I;
    spk = (m - s > TH) ? 1.f : 0.f;
}

// ============ weight prep: fp32 OIHW -> 3-term bf16 [term][tap][co][ci] ============
__global__ __launch_bounds__(256) void k_prep(const float* __restrict__ W,
                                              unsigned short* __restrict__ Ws,
                                              int CO, int CI) {
    int idx = blockIdx.x * 256 + threadIdx.x;
    int total = CO * CI * 9;
    if (idx >= total) return;
    int tap = idx % 9, tmp = idx / 9, ci = tmp % CI, co = tmp / CI;
    float w = W[((size_t)co * CI + ci) * 9 + tap];
    __hip_bfloat16 h = __float2bfloat16(w);
    float hf = __bfloat162float(h);
    __hip_bfloat16 mdd = __float2bfloat16(w - hf);
    float mf = __bfloat162float(mdd);
    __hip_bfloat16 lo = __float2bfloat16(w - hf - mf);
    size_t base = ((size_t)tap * CO + co) * CI + ci;
    size_t stride = (size_t)9 * CO * CI;
    Ws[base] = *(unsigned short*)&h;
    Ws[base + stride] = *(unsigned short*)&mdd;
    Ws[base + 2 * stride] = *(unsigned short*)&lo;
}

// ============ conv0T: all 16 steps, state in regs -> s0b_all [t][b][y][x][64ci] bf16 ====
// grid: 16b*8yt*8cog = 1024 blocks, 128 thr.
#define S0 68
__global__ __launch_bounds__(128) void k_conv0T(const float* __restrict__ in,
                                                const float* __restrict__ W0,
                                                unsigned short* __restrict__ s0b) {
    __shared__ float tile[2][10 * S0];
    int bid = blockIdx.x;
    int cog = bid & 7, yt = (bid >> 3) & 7, b = bid >> 6;
    int tid = threadIdx.x;
    int tx = (tid & 15) * 4, ty = tid >> 4;   // ty 0..7
    int y0 = yt * 8, y = y0 + ty;

    float m[8][4] = {}, s[8][4] = {};
    unsigned pmask = 0;                        // bit c*4+j

    for (int t = 0; t < T; t++) {
        if (t) __syncthreads();
        for (int i = tid; i < 2 * 660; i += 128) {
            int cl = i / 660, rem = i - cl * 660;
            int r = rem / 66, c = rem - r * 66;
            int gy = y0 + r - 1, gx = c - 1;
            float v = 0.f;
            if ((unsigned)gy < 64u && (unsigned)gx < 64u) {
                const float* src = in + ((size_t)((b * T + t) * 2 + cl)) * 4096;
                v = fminf(fmaxf(src[gy * 64 + gx], 0.f), 1.f);
            }
            tile[cl][r * S0 + c] = v;
        }
        __syncthreads();

        float acc[8][4] = {};
#pragma unroll
        for (int cl = 0; cl < 2; cl++) {
            const float* wb = W0 + ((size_t)cog * 8 * 2 + cl) * 9;
#pragma unroll
            for (int dy = 0; dy < 3; dy++) {
                float4 A = *(const float4*)&tile[cl][(ty + dy) * S0 + tx];
                float4 Bv = *(const float4*)&tile[cl][(ty + dy) * S0 + tx + 4];
                float r0 = A.x, r1 = A.y, r2 = A.z, r3 = A.w, r4 = Bv.x, r5 = Bv.y;
#pragma unroll
                for (int c = 0; c < 8; c++) {
                    const float* w = wb + (size_t)c * 2 * 9 + dy * 3;
                    float wa = w[0], wbx = w[1], wc = w[2];
                    acc[c][0] += wa * r0 + wbx * r1 + wc * r2;
                    acc[c][1] += wa * r1 + wbx * r2 + wc * r3;
                    acc[c][2] += wa * r2 + wbx * r3 + wc * r4;
                    acc[c][3] += wa * r3 + wbx * r4 + wc * r5;
                }
            }
        }

        unsigned newmask = 0;
        unsigned short* s0p = s0b + ((size_t)(t * 16 + b) * 4096) * 64;
#pragma unroll
        for (int j = 0; j < 4; j++) {
            short8 sv;
#pragma unroll
            for (int c = 0; c < 8; c++) {
                int bit = c * 4 + j;
                float p = (pmask >> bit) & 1 ? 1.f : 0.f;
                float spk;
                srm(m[c][j], s[c][j], p, acc[c][j], spk);
                bool on = spk > 0.5f;
                if (on) newmask |= 1u << bit;
                sv[c] = on ? (short)SPK1 : (short)0;
            }
            *(short8*)(s0p + ((size_t)(y * 64 + tx + j)) * 64 + cog * 8) = sv;
        }
        pmask = newmask;
    }
}

// ============ conv1T MFMA: all t, state in regs, halo-baked LDS A-tile, fused pool ====
// grid 1024 (XCD-pinned by b), 256 thr (4 waves). Block: 16 co x 8 rows x 64 x.
// atile chunk-major [c][r][x]: 8c x 10r x 66x short8 = 84,480 B; wlds 55,296 B.
__global__ __launch_bounds__(256, 1) void k_conv1T(const unsigned short* __restrict__ s0b,
                                                   const unsigned short* __restrict__ W1s,
                                                   unsigned short* __restrict__ p1b) {
    __shared__ short8 atile[5280];
    __shared__ short8 wlds[3456];
    int bid = blockIdx.x;
    int xcd = bid & 7, rest = bid >> 3;        // rest 0..127
    int b = ((rest & 1) << 3) | xcd;
    int yq = (rest >> 1) & 7;
    int cog = (rest >> 4) & 7;
    int tid = threadIdx.x;
    int lane = tid & 63, wv = tid >> 6;
    int n = lane & 15, q = lane >> 4;
    int y0 = yq * 8;

    const short8 zf = {0, 0, 0, 0, 0, 0, 0, 0};
    // zero whole A-tile once (halo cells stay zero forever)
    for (int i = tid; i < 5280; i += 256) atile[i] = zf;
    for (int idx = tid; idx < 3456; idx += 256) {
        int nn = idx & 15, qq = (idx >> 4) & 3;
        int rem = idx >> 6;                     // (kc*9+tap)*3+tm
        int tm = rem % 3, rem2 = rem / 3;
        int tap = rem2 % 9, kc = rem2 / 9;
        wlds[idx] = *(const short8*)(W1s +
            ((size_t)(tm * 9 + tap) * 128 + cog * 16 + nn) * 64 + kc * 32 + qq * 8);
    }

    int yr = yq * 4 + wv;
    int co = cog * 16 + n;

    float sm[2][4][4] = {}, ss[2][4][4] = {};
    unsigned pmask = 0;                         // bit (yo*4+xt)*4 + r

    for (int t = 0; t < T; t++) {
        __syncthreads();   // previous compute done; zero-init/wlds visible
        const unsigned short* sb = s0b + ((size_t)(t * 16 + b) * 4096) * 64;
        // stage valid cells: r in tile <-> gy = y0-1+r; x64 0..63 -> tile x = x64+1
        for (int i = tid; i < 5120; i += 256) {
            int c = i & 7, x64 = (i >> 3) & 63, r = i >> 9;   // r wave-uniform
            int gy = y0 - 1 + r;
            if ((unsigned)gy < 64u) {
                short8 v = *(const short8*)(sb + ((size_t)(gy * 64 + x64)) * 64 + c * 8);
                atile[c * 660 + r * 66 + x64 + 1] = v;
            }
        }
        __syncthreads();

        f32x4 acc[2][4];
#pragma unroll
        for (int i = 0; i < 2; i++)
#pragma unroll
            for (int j = 0; j < 4; j++) acc[i][j] = (f32x4){0.f, 0.f, 0.f, 0.f};

#pragma unroll
        for (int kc = 0; kc < 2; kc++) {
            int cbase = (kc * 4 + q) * 660;
#pragma unroll
            for (int dy = 0; dy < 3; dy++) {
                int rA = wv * 2 + dy, rB = rA + 1;   // tile rows (OOB rows are zeros)
#pragma unroll
                for (int dx = 0; dx < 3; dx++) {
                    int tap = dy * 3 + dx;
                    short8 AfA[4], AfB[4];
#pragma unroll
                    for (int xt = 0; xt < 4; xt++) {
                        int x = xt * 16 + n + dx;    // tile x (halo baked)
                        AfA[xt] = atile[cbase + rA * 66 + x];
                        AfB[xt] = atile[cbase + rB * 66 + x];
                    }
#pragma unroll
                    for (int tm = 0; tm < 3; tm++) {
                        short8 Bf = wlds[((kc * 9 + tap) * 3 + tm) * 64 + q * 16 + n];
#pragma unroll
                        for (int xt = 0; xt < 4; xt++) {
                            acc[0][xt] = __builtin_amdgcn_mfma_f32_16x16x32_bf16(AfA[xt], Bf, acc[0][xt], 0, 0, 0);
                            acc[1][xt] = __builtin_amdgcn_mfma_f32_16x16x32_bf16(AfB[xt], Bf, acc[1][xt], 0, 0, 0);
                        }
                    }
                }
            }
        }

        unsigned newmask = 0;
#pragma unroll
        for (int yo = 0; yo < 2; yo++)
#pragma unroll
            for (int xt = 0; xt < 4; xt++)
#pragma unroll
                for (int r = 0; r < 4; r++) {
                    int bit = (yo * 4 + xt) * 4 + r;
                    float p = (pmask >> bit) & 1 ? 1.f : 0.f;
                    float spk;
                    srm(sm[yo][xt][r], ss[yo][xt][r], p, acc[yo][xt][r], spk);
                    if (spk > 0.5f) newmask |= 1u << bit;
                }
        pmask = newmask;

        unsigned short* pb = p1b + (((size_t)(t * 16 + b) * 1024) + yr * 32) * 128 + co;
#pragma unroll
        for (int xt = 0; xt < 4; xt++)
#pragma unroll
            for (int rp = 0; rp < 2; rp++) {
                int i0 = (0 * 4 + xt) * 4 + 2 * rp;
                int i1 = (1 * 4 + xt) * 4 + 2 * rp;
                unsigned on = ((newmask >> i0) | (newmask >> (i0 + 1)) |
                               (newmask >> i1) | (newmask >> (i1 + 1))) & 1u;
                int xp = xt * 8 + q * 2 + rp;
                pb[(size_t)xp * 128] = on ? SPK1 : (unsigned short)0;
            }
    }
}

// ============ conv2T MFMA: all t, halo-baked LDS A-tile (2 ci-phases), fused pool ======
// grid 512 (XCD-pinned by b), 256 thr. Block: 16 co x 8 rows x 32 x.
// atile [c][r][x]: 8c x 10r x 34x = 43,520 B (half ci per phase); wlds 110,592 B.
__global__ __launch_bounds__(256, 1) void k_conv2T(const unsigned short* __restrict__ p1b,
                                                   const unsigned short* __restrict__ W2s,
                                                   float* __restrict__ p2) {
    __shared__ short8 atile[2720];
    __shared__ short8 wlds[6912];
    int bid = blockIdx.x;
    int xcd = bid & 7, rest = bid >> 3;        // rest 0..63
    int b = ((rest & 1) << 3) | xcd;
    int yq = (rest >> 1) & 3;
    int cog = (rest >> 3) & 7;
    int tid = threadIdx.x;
    int lane = tid & 63, wv = tid >> 6;
    int n = lane & 15, q = lane >> 4;
    int y0 = yq * 8;

    const short8 zf = {0, 0, 0, 0, 0, 0, 0, 0};
    for (int i = tid; i < 2720; i += 256) atile[i] = zf;
    for (int idx = tid; idx < 6912; idx += 256) {
        int nn = idx & 15, qq = (idx >> 4) & 3;
        int rem = idx >> 6;                     // (kc*9+tap)*3+tm
        int tm = rem % 3, rem2 = rem / 3;
        int tap = rem2 % 9, kc = rem2 / 9;
        wlds[idx] = *(const short8*)(W2s +
            ((size_t)(tm * 9 + tap) * 128 + cog * 16 + nn) * 128 + kc * 32 + qq * 8);
    }

    int yr = yq * 4 + wv;
    int co = cog * 16 + n;

    float sm[2][2][4] = {}, ss[2][2][4] = {};
    unsigned pmask = 0;                         // bit (yo*2+xt)*4 + r

    for (int t = 0; t < T; t++) {
        const unsigned short* sb = p1b + ((size_t)(t * 16 + b) * 1024) * 128;
        f32x4 acc[2][2];
#pragma unroll
        for (int i = 0; i < 2; i++)
#pragma unroll
            for (int j = 0; j < 2; j++) acc[i][j] = (f32x4){0.f, 0.f, 0.f, 0.f};

#pragma unroll
        for (int ph = 0; ph < 2; ph++) {
            __syncthreads();   // prev compute done before restaging
            for (int i = tid; i < 2560; i += 256) {
                int c = i & 7, x32 = (i >> 3) & 31, r = i >> 8;   // r wave-uniform
                int gy = y0 - 1 + r;
                if ((unsigned)gy < 32u) {
                    short8 v = *(const short8*)(sb + ((size_t)(gy * 32 + x32)) * 128 + (ph * 8 + c) * 8);
                    atile[c * 340 + r * 34 + x32 + 1] = v;
                }
            }
            __syncthreads();

#pragma unroll
            for (int kci = 0; kci < 2; kci++) {
                int kc = ph * 2 + kci;
                int cbase = (kci * 4 + q) * 340;
#pragma unroll
                for (int dy = 0; dy < 3; dy++) {
                    int rA = wv * 2 + dy, rB = rA + 1;
#pragma unroll
                    for (int dx = 0; dx < 3; dx++) {
                        int tap = dy * 3 + dx;
                        short8 AfA[2], AfB[2];
#pragma unroll
                        for (int xt = 0; xt < 2; xt++) {
                            int x = xt * 16 + n + dx;
                            AfA[xt] = atile[cbase + rA * 34 + x];
                            AfB[xt] = atile[cbase + rB * 34 + x];
                        }
#pragma unroll
                        for (int tm = 0; tm < 3; tm++) {
                            short8 Bf = wlds[((kc * 9 + tap) * 3 + tm) * 64 + q * 16 + n];
#pragma unroll
                            for (int xt = 0; xt < 2; xt++) {
                                acc[0][xt] = __builtin_amdgcn_mfma_f32_16x16x32_bf16(AfA[xt], Bf, acc[0][xt], 0, 0, 0);
                                acc[1][xt] = __builtin_amdgcn_mfma_f32_16x16x32_bf16(AfB[xt], Bf, acc[1][xt], 0, 0, 0);
                            }
                        }
                    }
                }
            }
        }

        unsigned newmask = 0;
#pragma unroll
        for (int yo = 0; yo < 2; yo++)
#pragma unroll
            for (int xt = 0; xt < 2; xt++)
#pragma unroll
                for (int r = 0; r < 4; r++) {
                    int bit = (yo * 2 + xt) * 4 + r;
                    float p = (pmask >> bit) & 1 ? 1.f : 0.f;
                    float spk;
                    srm(sm[yo][xt][r], ss[yo][xt][r], p, acc[yo][xt][r], spk);
                    if (spk > 0.5f) newmask |= 1u << bit;
                }
        pmask = newmask;

        float* pp = p2 + (size_t)(t * 16 + b) * 32768 + (size_t)co * 256 + yr * 16;
#pragma unroll
        for (int xt = 0; xt < 2; xt++)
#pragma unroll
            for (int rp = 0; rp < 2; rp++) {
                int i0 = (0 * 2 + xt) * 4 + 2 * rp;
                int i1 = (1 * 2 + xt) * 4 + 2 * rp;
                unsigned on = ((newmask >> i0) | (newmask >> (i0 + 1)) |
                               (newmask >> i1) | (newmask >> (i1 + 1))) & 1u;
                int xp = xt * 8 + q * 2 + rp;
                pp[xp] = on ? 1.f : 0.f;
            }
    }
}

// ============ fc3: per-t grid. p2[t][16,32768] @ W3^T -> I3p[t][ks][8192] ============
// grid 8192 = 32 ot x 16 ks x 16 t; block 256 (4 waves). Wave: 4 o x 16 b, lanes along k.
__global__ __launch_bounds__(256) void k_fc3(const float* __restrict__ p2,
                                             const float* __restrict__ W3,
                                             float* __restrict__ I3p) {
    int ot = blockIdx.x & 31, ks = (blockIdx.x >> 5) & 15, t = blockIdx.x >> 9;
    int lane = threadIdx.x & 63, wv = threadIdx.x >> 6;
    int o0 = ot * 16 + wv * 4;
    int kb = ks * 2048 + lane * 4;

    float acc[4][16];
#pragma unroll
    for (int o = 0; o < 4; o++)
#pragma unroll
        for (int bb = 0; bb < 16; bb++) acc[o][bb] = 0.f;

#pragma unroll
    for (int kk = 0; kk < 8; kk++) {
        int k = kb + kk * 256;
        float4 w4[4];
#pragma unroll
        for (int o = 0; o < 4; o++)
            w4[o] = *(const float4*)(W3 + (size_t)(o0 + o) * 32768 + k);
#pragma unroll
        for (int bb = 0; bb < 16; bb++) {
            float4 pv = *(const float4*)(p2 + (size_t)(t * 16 + bb) * 32768 + k);
#pragma unroll
            for (int o = 0; o < 4; o++)
                acc[o][bb] += w4[o].x * pv.x + w4[o].y * pv.y +
                              w4[o].z * pv.z + w4[o].w * pv.w;
        }
    }
#pragma unroll
    for (int o = 0; o < 4; o++)
#pragma unroll
        for (int bb = 0; bb < 16; bb++)
#pragma unroll
            for (int d = 1; d < 64; d <<= 1)
                acc[o][bb] += __shfl_xor(acc[o][bb], d);

    int bb = lane & 15, osl = lane >> 4;
    float v = 0.f;
#pragma unroll
    for (int o = 0; o < 4; o++)
#pragma unroll
        for (int b2 = 0; b2 < 16; b2++)
            if (osl == o && bb == b2) v = acc[o][b2];
    I3p[((size_t)(t * 16 + ks)) * 8192 + bb * 512 + o0 + osl] = v;
}

// ============ srm3T: per neuron, scan t: reduce 16 partials + SRM -> sp3_all [t][8192]
__global__ __launch_bounds__(256) void k_srm3T(const float* __restrict__ I3p,
                                               float* __restrict__ sp3) {
    int idx = blockIdx.x * 256 + threadIdx.x;    // 8192
    float m = 0.f, s = 0.f, p = 0.f;
    for (int t = 0; t < T; t++) {
        float I = 0.f;
#pragma unroll
        for (int ks = 0; ks < 16; ks++) I += I3p[((size_t)(t * 16 + ks)) * 8192 + idx];
        float spk;
        srm(m, s, p, I, spk);
        p = spk;
        sp3[t * 8192 + idx] = spk;
    }
}

// ============ fc4g: I4[t*16+b][11] = sp3[t][b] @ W4^T ============
__global__ __launch_bounds__(256) void k_fc4g(const float* __restrict__ sp3,
                                              const float* __restrict__ W4,
                                              float* __restrict__ I4) {
    int t = blockIdx.x, tid = threadIdx.x;
    if (tid >= 176) return;
    int b = tid / 11, o = tid - b * 11;
    const float4* a = (const float4*)(sp3 + (size_t)t * 8192 + b * 512);
    const float4* w = (const float4*)(W4 + o * 512);
    float acc = 0.f;
    for (int k = 0; k < 128; k++) {
        float4 x = a[k], y = w[k];
        acc += x.x * y.x + x.y * y.y + x.z * y.z + x.w * y.w;
    }
    I4[(size_t)(t * 16 + b) * 11 + o] = acc;
}

// ============ fc4s: scan t with SRM, write out ============
__global__ __launch_bounds__(256) void k_fc4s(const float* __restrict__ I4,
                                              float* __restrict__ out) {
    int tid = threadIdx.x;
    if (tid >= 176) return;
    int b = tid / 11, o = tid - b * 11;
    float m = 0.f, s = 0.f, p = 0.f, sum = 0.f;
    for (int t = 0; t < T; t++) {
        float I = I4[(size_t)(t * 16 + b) * 11 + o];
        float spk;
        srm(m, s, p, I, spk);
        p = spk;
        sum += spk;
    }
    out[tid] = sum * 0.0625f;   // exact: integer count / 16
}

extern "C" void kernel_launch(void* const* d_in, const int* in_sizes, int n_in,
                              void* d_out, int out_size, void* d_ws, size_t ws_size,
                              hipStream_t stream) {
    const float* in = (const float*)d_in[0];
    const float* W0 = (const float*)d_in[1];
    const float* W1 = (const float*)d_in[2];
    const float* W2 = (const float*)d_in[3];
    const float* W3 = (const float*)d_in[4];
    const float* W4 = (const float*)d_in[5];
    float* out = (float*)d_out;
    char* ws = (char*)d_ws;

    size_t off = 0;
    auto alloc = [&](size_t bytes) {
        void* p = ws + off;
        off += (bytes + 255) & ~(size_t)255;
        return p;
    };
    // all buffers fully written before read each launch -> no memsets needed
    unsigned short* s0b = (unsigned short*)alloc((size_t)256 * 4096 * 64 * 2);   // 134.2 MB
    unsigned short* p1b = (unsigned short*)alloc((size_t)256 * 1024 * 128 * 2);  // 67.1 MB
    float* p2  = (float*)alloc((size_t)256 * 32768 * 4);                          // 33.6 MB
    float* I3p = (float*)alloc((size_t)256 * 8192 * 4);                           // 8.4 MB
    float* sp3 = (float*)alloc((size_t)16 * 8192 * 4);
    float* I4  = (float*)alloc((size_t)256 * 11 * 4);
    unsigned short* W1s = (unsigned short*)alloc((size_t)3 * 9 * 128 * 64 * 2);
    unsigned short* W2s = (unsigned short*)alloc((size_t)3 * 9 * 128 * 128 * 2);

    k_prep<<<(9 * 128 * 64 + 255) / 256, 256, 0, stream>>>(W1, W1s, 128, 64);
    k_prep<<<(9 * 128 * 128 + 255) / 256, 256, 0, stream>>>(W2, W2s, 128, 128);

    k_conv0T<<<16 * 8 * 8, 128, 0, stream>>>(in, W0, s0b);
    k_conv1T<<<1024, 256, 0, stream>>>(s0b, W1s, p1b);
    k_conv2T<<<512, 256, 0, stream>>>(p1b, W2s, p2);
    k_fc3<<<32 * 16 * 16, 256, 0, stream>>>(p2, W3, I3p);
    k_srm3T<<<8192 / 256, 256, 0, stream>>>(I3p, sp3);
    k_fc4g<<<16, 256, 0, stream>>>(sp3, W4, I4);
    k_fc4s<<<1, 256, 0, stream>>>(I4, out);
}